// Round 5
// baseline (9910.644 us; speedup 1.0000x reference)
//
#include <hip/hip_runtime.h>
#include <hip/hip_bf16.h>

#define NEG 0.2f
#define LRELU(x) ((x) > 0.f ? (x) : NEG*(x))

typedef __hip_bfloat16 bf16;

__device__ __forceinline__ float b2f(bf16 v){ return __bfloat162float(v); }
__device__ __forceinline__ float ldf(const float* p, size_t i){ return p[i]; }
__device__ __forceinline__ float ldf(const bf16* p, size_t i){ return __bfloat162float(p[i]); }

__device__ __forceinline__ float wred(float v){
#pragma unroll
  for(int o=32;o>0;o>>=1) v += __shfl_down(v,o);
  return v; // valid at lane 0
}

__device__ __forceinline__ void atomAddF(float* p, float v){
  __hip_atomic_fetch_add(p, v, __ATOMIC_RELAXED, __HIP_MEMORY_SCOPE_AGENT);
}

// h[n,:] = (relu?)xin[n,:] @ Whl[t[n]] + bhl[t[n]]   (bf16 out, f32 accum)
// also hi_s[n]=h·Watt[0:64], hj_s[n]=h·Watt[64:128]
template<typename TIN, bool RELU_IN>
__global__ __launch_bounds__(256) void k_hlin(
    const TIN* __restrict__ xin, const int* __restrict__ ntype,
    const float* __restrict__ Whl, const float* __restrict__ bhl,
    const float* __restrict__ Watt,
    bf16* __restrict__ h, float* __restrict__ hi_s, float* __restrict__ hj_s,
    int nN)
{
  int wid  = (blockIdx.x*blockDim.x + threadIdx.x) >> 6;
  int lane = threadIdx.x & 63;
  if (wid >= nN) return;
  int t = ntype[wid];
  float xv = ldf(xin, (size_t)wid*64 + lane);
  if (RELU_IN) xv = fmaxf(xv, 0.f);
  const float* W = Whl + (size_t)t*4096;
  float acc = bhl[t*64 + lane];
#pragma unroll
  for (int i=0;i<64;i++) acc = fmaf(__shfl(xv, i), W[i*64 + lane], acc);
  h[(size_t)wid*64 + lane] = __float2bfloat16(acc);
  float pi = wred(acc * Watt[lane]);
  float pj = wred(acc * Watt[64 + lane]);
  if (lane==0){ hi_s[wid]=pi; hj_s[wid]=pj; }
}

// ea_out[e,:] = lrelu((relu?)ain[e,:] @ Wea)  (bf16 out; in-place safe: one wave owns its row)
// logits[e] = ea_out·Watt[132:196]   (f32, from unrounded acc)
template<typename TIN, bool RELU_IN, int F_IN>
__global__ __launch_bounds__(256) void k_ea(
    const TIN* __restrict__ ain, const float* __restrict__ Wea,
    const float* __restrict__ Watt,
    bf16* __restrict__ eout, float* __restrict__ logits, int nE)
{
  int wid  = (blockIdx.x*blockDim.x + threadIdx.x) >> 6;
  int lane = threadIdx.x & 63;
  if (wid >= nE) return;
  float av = 0.f;
  if (lane < F_IN) {
    av = ldf(ain, (size_t)wid*F_IN + lane);
    if (RELU_IN) av = fmaxf(av, 0.f);
  }
  float acc = 0.f;
#pragma unroll
  for (int i=0;i<F_IN;i++) acc = fmaf(__shfl(av,i), Wea[i*64 + lane], acc);
  acc = LRELU(acc);
  eout[(size_t)wid*64 + lane] = __float2bfloat16(acc);
  float p = wred(acc * Watt[132 + lane]);
  if (lane==0) logits[wid] = p;
}

// fused: l = lrelu(partial + hi_s[dst] + hj_s[src] + lrelu(Ete[et])·Watt[128:132])
//        ex = exp(min(l,60)); logits[e]=ex; segsum[dst]+=ex
// (no max pass: logits are O(1); softmax is shift-invariant so result identical)
__global__ __launch_bounds__(256) void k_att(
    const int* __restrict__ src, const int* __restrict__ dst,
    const int* __restrict__ etype, const float* __restrict__ Ete,
    const float* __restrict__ Watt,
    const float* __restrict__ hi_s, const float* __restrict__ hj_s,
    float* __restrict__ logits, float* __restrict__ segsum, int nE)
{
  int e = blockIdx.x*blockDim.x + threadIdx.x;
  if (e >= nE) return;
  int d = dst[e], s = src[e], t = etype[e];
  float wt = 0.f;
#pragma unroll
  for (int k=0;k<4;k++){ float v = Ete[t*4+k]; v = LRELU(v); wt = fmaf(v, Watt[128+k], wt); }
  float l = logits[e] + hi_s[d] + hj_s[s] + wt;
  l = LRELU(l);
  float ex = __expf(fminf(l, 60.f));
  logits[e] = ex;
  atomAddF(&segsum[d], ex);
}

// segsum[n] := 1/(segsum[n]+1e-16)
__global__ __launch_bounds__(256) void k_inv(float* __restrict__ segsum, int nN)
{
  int n = blockIdx.x*blockDim.x + threadIdx.x;
  if (n >= nN) return;
  segsum[n] = 1.f / (segsum[n] + 1e-16f);
}

// out[dst,:] += alpha * (h[src]@Wlin[:64] + ea[e]@Wlin[64:])   (f32 atomic accum)
__global__ __launch_bounds__(256) void k_msg(
    const int* __restrict__ src, const int* __restrict__ dst,
    const bf16* __restrict__ h, const bf16* __restrict__ ea,
    const float* __restrict__ Wlin,
    const float* __restrict__ ex, const float* __restrict__ inv_segsum,
    float* __restrict__ out, int nE)
{
  int wid  = (blockIdx.x*blockDim.x + threadIdx.x) >> 6;
  int lane = threadIdx.x & 63;
  if (wid >= nE) return;
  int s = src[wid], d = dst[wid];
  float hv = b2f(h[(size_t)s*64 + lane]);
  float ev = b2f(ea[(size_t)wid*64 + lane]);
  float acc = 0.f;
#pragma unroll
  for (int i=0;i<64;i++) acc = fmaf(__shfl(hv,i), Wlin[i*64 + lane], acc);
#pragma unroll
  for (int i=0;i<64;i++) acc = fmaf(__shfl(ev,i), Wlin[(64+i)*64 + lane], acc);
  float a = 0.f;
  if (lane==0) a = ex[wid] * inv_segsum[d];
  a = __shfl(a, 0);
  atomAddF(&out[(size_t)d*64 + lane], acc * a);
}

// x_out[n] = relu(outA[n])·Wnc[t] + bnc[t]   (f32 out)
__global__ __launch_bounds__(256) void k_xout(
    const float* __restrict__ hin, const int* __restrict__ ntype,
    const float* __restrict__ Wnc, const float* __restrict__ bnc,
    float* __restrict__ xout, int nN)
{
  int wid  = (blockIdx.x*blockDim.x + threadIdx.x) >> 6;
  int lane = threadIdx.x & 63;
  if (wid >= nN) return;
  int t = ntype[wid];
  float v = fmaxf(hin[(size_t)wid*64 + lane], 0.f);
  float p = wred(v * Wnc[t*64 + lane]);
  if (lane==0) xout[wid] = p + bnc[t];
}

// e_out[e] = relu(ea[e])·Wec[t] + bec[t]   (f32 out)
__global__ __launch_bounds__(256) void k_eout(
    const bf16* __restrict__ ein, const int* __restrict__ etype,
    const float* __restrict__ Wec, const float* __restrict__ bec,
    float* __restrict__ eout, int nE)
{
  int wid  = (blockIdx.x*blockDim.x + threadIdx.x) >> 6;
  int lane = threadIdx.x & 63;
  if (wid >= nE) return;
  int t = etype[wid];
  float v = fmaxf(b2f(ein[(size_t)wid*64 + lane]), 0.f);
  float p = wred(v * Wec[t*64 + lane]);
  if (lane==0) eout[wid] = p + bec[t];
}

extern "C" void kernel_launch(void* const* d_in, const int* in_sizes, int n_in,
                              void* d_out, int out_size, void* d_ws, size_t ws_size,
                              hipStream_t stream) {
  const float* x      = (const float*)d_in[0];
  const int*   eidx   = (const int*) d_in[1];
  const int*   ntype  = (const int*) d_in[2];
  const int*   etype  = (const int*) d_in[3];
  const float* eattr  = (const float*)d_in[4];
  const float* Whl[3]  = {(const float*)d_in[5],  (const float*)d_in[11], (const float*)d_in[17]};
  const float* bhl[3]  = {(const float*)d_in[6],  (const float*)d_in[12], (const float*)d_in[18]};
  const float* Ete[3]  = {(const float*)d_in[7],  (const float*)d_in[13], (const float*)d_in[19]};
  const float* Wea[3]  = {(const float*)d_in[8],  (const float*)d_in[14], (const float*)d_in[20]};
  const float* Watt[3] = {(const float*)d_in[9],  (const float*)d_in[15], (const float*)d_in[21]};
  const float* Wlin[3] = {(const float*)d_in[10], (const float*)d_in[16], (const float*)d_in[22]};
  const float* Wnc = (const float*)d_in[23];
  const float* bnc = (const float*)d_in[24];
  const float* Wec = (const float*)d_in[25];
  const float* bec = (const float*)d_in[26];

  const int nN = in_sizes[2];      // 50000
  const int nE = in_sizes[3];      // 800000
  const int* srcI = eidx;
  const int* dstI = eidx + nE;

  // workspace layout (f32 words)
  float* ws = (float*)d_ws;
  size_t o = 0;
  bf16*  h      = (bf16*)(ws + o); o += (size_t)nN*32;  // N*64 bf16
  float* outA   = ws + o;          o += (size_t)nN*64;  // f32 (atomic accum)
  float* hi_s   = ws + o;          o += (size_t)nN;
  float* hj_s   = ws + o;          o += (size_t)nN;
  float* logit  = ws + o;          o += (size_t)nE;
  float* segsum = ws + o;          o += (size_t)nN;
  bf16*  ea     = (bf16*)(ws + o); o += (size_t)nE*32;  // E*64 bf16, in-place across layers

  dim3 blk(256);
  int nodeWB = (int)(((size_t)nN*64 + 255)/256);   // wave-per-node
  int edgeWB = (int)(((size_t)nE*64 + 255)/256);   // wave-per-edge
  int edgeTB = (nE + 255)/256;                     // thread-per-edge
  int nodeTB = (nN + 255)/256;                     // thread-per-node

  for (int L = 0; L < 3; ++L) {
    if (L == 0)
      k_hlin<float,false><<<nodeWB, blk, 0, stream>>>(x,    ntype, Whl[L], bhl[L], Watt[L], h, hi_s, hj_s, nN);
    else
      k_hlin<float,true ><<<nodeWB, blk, 0, stream>>>(outA, ntype, Whl[L], bhl[L], Watt[L], h, hi_s, hj_s, nN);

    if (L == 0)
      k_ea<float,false,32><<<edgeWB, blk, 0, stream>>>(eattr, Wea[L], Watt[L], ea, logit, nE);
    else
      k_ea<bf16 ,true ,64><<<edgeWB, blk, 0, stream>>>(ea,    Wea[L], Watt[L], ea, logit, nE);

    hipMemsetAsync(segsum, 0, (size_t)nN*4, stream);
    k_att<<<edgeTB, blk, 0, stream>>>(srcI, dstI, etype, Ete[L], Watt[L], hi_s, hj_s, logit, segsum, nE);
    k_inv<<<nodeTB, blk, 0, stream>>>(segsum, nN);

    hipMemsetAsync(outA, 0, (size_t)nN*64*4, stream);
    k_msg<<<edgeWB, blk, 0, stream>>>(srcI, dstI, h, ea, Wlin[L], logit, segsum, outA, nE);
  }

  float* xout = (float*)d_out;
  k_xout<<<nodeWB, blk, 0, stream>>>(outA, ntype, Wnc, bnc, xout, nN);
  k_eout<<<edgeWB, blk, 0, stream>>>(ea,   etype, Wec, bec, xout + nN, nE);
}

// Round 7
// 2691.848 us; speedup vs baseline: 3.6817x; 3.6817x over previous
//
#include <hip/hip_runtime.h>
#include <hip/hip_bf16.h>

#define NEG 0.2f
#define LRELU(x) ((x) > 0.f ? (x) : NEG*(x))

typedef __hip_bfloat16 bf16;

__device__ __forceinline__ float b2f(bf16 v){ return __bfloat162float(v); }
__device__ __forceinline__ float ldf(const float* p, size_t i){ return p[i]; }
__device__ __forceinline__ float ldf(const bf16* p, size_t i){ return __bfloat162float(p[i]); }

__device__ __forceinline__ float wred(float v){
#pragma unroll
  for(int o=32;o>0;o>>=1) v += __shfl_down(v,o);
  return v; // valid at lane 0
}

__device__ __forceinline__ float atomAddF(float* p, float v){
  return __hip_atomic_fetch_add(p, v, __ATOMIC_RELAXED, __HIP_MEMORY_SCOPE_AGENT);
}
__device__ __forceinline__ int atomAddI(int* p, int v){
  return __hip_atomic_fetch_add(p, v, __ATOMIC_RELAXED, __HIP_MEMORY_SCOPE_AGENT);
}

// ---------------- CSR build (dst is layer-invariant; built once per call) ----------------

__global__ __launch_bounds__(256) void k_hist(
    const int* __restrict__ dst, int* __restrict__ deg, int nE)
{
  int e = blockIdx.x*blockDim.x + threadIdx.x;
  if (e >= nE) return;
  atomAddI(&deg[dst[e]], 1);
}

// single-block exclusive scan: off[0..nN] from deg[0..nN-1]
__global__ __launch_bounds__(1024) void k_scan(
    const int* __restrict__ deg, int* __restrict__ off, int nN)
{
  __shared__ int part[1024];
  int tid = threadIdx.x;
  int chunk = (nN + 1023) / 1024;
  int lo = tid*chunk, hi = min((tid+1)*chunk, nN);
  int s = 0;
  for (int i=lo;i<hi;i++) s += deg[i];
  part[tid] = s;
  __syncthreads();
  for (int d=1; d<1024; d<<=1){
    int v = (tid>=d) ? part[tid-d] : 0;
    __syncthreads();
    part[tid] += v;
    __syncthreads();
  }
  int run = (tid==0) ? 0 : part[tid-1];
  for (int i=lo;i<hi;i++){ off[i] = run; run += deg[i]; }
  if (tid==1023) off[nN] = part[1023];
}

// cnt must be zeroed before launch; eid[off[d]+k] = edge ids with dst==d
__global__ __launch_bounds__(256) void k_scatter(
    const int* __restrict__ dst, const int* __restrict__ off,
    int* __restrict__ cnt, int* __restrict__ eid, int nE)
{
  int e = blockIdx.x*blockDim.x + threadIdx.x;
  if (e >= nE) return;
  int d = dst[e];
  int p = atomAddI(&cnt[d], 1);
  eid[off[d] + p] = e;
}

// ---------------- per-layer kernels ----------------

// h[n,:] = (relu?)xin[n,:] @ Whl[t[n]] + bhl[t[n]]   (bf16 out, f32 accum)
// also hi_s[n]=h·Watt[0:64], hj_s[n]=h·Watt[64:128]
template<typename TIN, bool RELU_IN>
__global__ __launch_bounds__(256) void k_hlin(
    const TIN* __restrict__ xin, const int* __restrict__ ntype,
    const float* __restrict__ Whl, const float* __restrict__ bhl,
    const float* __restrict__ Watt,
    bf16* __restrict__ h, float* __restrict__ hi_s, float* __restrict__ hj_s,
    int nN)
{
  int wid  = (blockIdx.x*blockDim.x + threadIdx.x) >> 6;
  int lane = threadIdx.x & 63;
  if (wid >= nN) return;
  int t = ntype[wid];
  float xv = ldf(xin, (size_t)wid*64 + lane);
  if (RELU_IN) xv = fmaxf(xv, 0.f);
  const float* W = Whl + (size_t)t*4096;
  float acc = bhl[t*64 + lane];
#pragma unroll
  for (int i=0;i<64;i++) acc = fmaf(__shfl(xv, i), W[i*64 + lane], acc);
  h[(size_t)wid*64 + lane] = __float2bfloat16(acc);
  float pi = wred(acc * Watt[lane]);
  float pj = wred(acc * Watt[64 + lane]);
  if (lane==0){ hi_s[wid]=pi; hj_s[wid]=pj; }
}

// ea_out[e,:] = lrelu((relu?)ain[e,:] @ Wea)  (bf16 out; in-place safe: one wave owns its row)
// logits[e] = ea_out·Watt[132:196]   (f32, from unrounded acc)
template<typename TIN, bool RELU_IN, int F_IN>
__global__ __launch_bounds__(256) void k_ea(
    const TIN* __restrict__ ain, const float* __restrict__ Wea,
    const float* __restrict__ Watt,
    bf16* __restrict__ eout, float* __restrict__ logits, int nE)
{
  int wid  = (blockIdx.x*blockDim.x + threadIdx.x) >> 6;
  int lane = threadIdx.x & 63;
  if (wid >= nE) return;
  float av = 0.f;
  if (lane < F_IN) {
    av = ldf(ain, (size_t)wid*F_IN + lane);
    if (RELU_IN) av = fmaxf(av, 0.f);
  }
  float acc = 0.f;
#pragma unroll
  for (int i=0;i<F_IN;i++) acc = fmaf(__shfl(av,i), Wea[i*64 + lane], acc);
  acc = LRELU(acc);
  eout[(size_t)wid*64 + lane] = __float2bfloat16(acc);
  float p = wred(acc * Watt[132 + lane]);
  if (lane==0) logits[wid] = p;
}

// fused: l = lrelu(partial + hi_s[dst] + hj_s[src] + lrelu(Ete[et])·Watt[128:132])
//        ex = exp(min(l,60)); logits[e]=ex; segsum[dst]+=ex
__global__ __launch_bounds__(256) void k_att(
    const int* __restrict__ src, const int* __restrict__ dst,
    const int* __restrict__ etype, const float* __restrict__ Ete,
    const float* __restrict__ Watt,
    const float* __restrict__ hi_s, const float* __restrict__ hj_s,
    float* __restrict__ logits, float* __restrict__ segsum, int nE)
{
  int e = blockIdx.x*blockDim.x + threadIdx.x;
  if (e >= nE) return;
  int d = dst[e], s = src[e], t = etype[e];
  float wt = 0.f;
#pragma unroll
  for (int k=0;k<4;k++){ float v = Ete[t*4+k]; v = LRELU(v); wt = fmaf(v, Watt[128+k], wt); }
  float l = logits[e] + hi_s[d] + hj_s[s] + wt;
  l = LRELU(l);
  float ex = __expf(fminf(l, 60.f));
  logits[e] = ex;
  atomAddF(&segsum[d], ex);
}

// segsum[n] := 1/(segsum[n]+1e-16)
__global__ __launch_bounds__(256) void k_inv(float* __restrict__ segsum, int nN)
{
  int n = blockIdx.x*blockDim.x + threadIdx.x;
  if (n >= nN) return;
  segsum[n] = 1.f / (segsum[n] + 1e-16f);
}

// CSR aggregation: u[n]=Σ α h[src], v[n]=Σ α ea[e]  → uv[n][0:64]=u, uv[n][64:128]=v (bf16)
__global__ __launch_bounds__(256) void k_agg(
    const int* __restrict__ off, const int* __restrict__ eid,
    const int* __restrict__ src,
    const bf16* __restrict__ h, const bf16* __restrict__ ea,
    const float* __restrict__ ex, const float* __restrict__ inv_segsum,
    bf16* __restrict__ uv, int nN)
{
  int wid  = (blockIdx.x*blockDim.x + threadIdx.x) >> 6;
  int lane = threadIdx.x & 63;
  if (wid >= nN) return;
  int beg = off[wid], end = off[wid+1];
  float inv = inv_segsum[wid];
  float au = 0.f, av = 0.f;
  int i = beg;
  int eC = 0, sC = 0; float aC = 0.f;
  if (i < end){ eC = eid[i]; sC = src[eC]; aC = ex[eC]; }
  while (i < end){
    int e = eC, s = sC; float a = aC * inv;
    int j = i + 1;
    if (j < end){ eC = eid[j]; sC = src[eC]; aC = ex[eC]; }  // prefetch next edge scalars
    float hv = b2f(h[(size_t)s*64 + lane]);
    float ev = b2f(ea[(size_t)e*64 + lane]);
    au = fmaf(a, hv, au);
    av = fmaf(a, ev, av);
    i = j;
  }
  uv[(size_t)wid*128 + lane]      = __float2bfloat16(au);
  uv[(size_t)wid*128 + 64 + lane] = __float2bfloat16(av);
}

// out[n] = u@Wlin[:64] + v@Wlin[64:]; out (f32) aliases uv (bf16) — wave-local read-before-write
__global__ __launch_bounds__(256) void k_mm(
    const bf16* uv, const float* __restrict__ Wlin, float* out, int nN)
{
  int wid  = (blockIdx.x*blockDim.x + threadIdx.x) >> 6;
  int lane = threadIdx.x & 63;
  if (wid >= nN) return;
  float u0 = b2f(uv[(size_t)wid*128 + lane]);
  float u1 = b2f(uv[(size_t)wid*128 + 64 + lane]);
  float acc = 0.f;
#pragma unroll
  for (int k=0;k<64;k++) acc = fmaf(__shfl(u0,k), Wlin[k*64 + lane], acc);
#pragma unroll
  for (int k=0;k<64;k++) acc = fmaf(__shfl(u1,k), Wlin[(64+k)*64 + lane], acc);
  out[(size_t)wid*64 + lane] = acc;
}

// x_out[n] = relu(outA[n])·Wnc[t] + bnc[t]   (f32 out)
__global__ __launch_bounds__(256) void k_xout(
    const float* __restrict__ hin, const int* __restrict__ ntype,
    const float* __restrict__ Wnc, const float* __restrict__ bnc,
    float* __restrict__ xout, int nN)
{
  int wid  = (blockIdx.x*blockDim.x + threadIdx.x) >> 6;
  int lane = threadIdx.x & 63;
  if (wid >= nN) return;
  int t = ntype[wid];
  float v = fmaxf(hin[(size_t)wid*64 + lane], 0.f);
  float p = wred(v * Wnc[t*64 + lane]);
  if (lane==0) xout[wid] = p + bnc[t];
}

// e_out[e] = relu(ea[e])·Wec[t] + bec[t]   (f32 out)
__global__ __launch_bounds__(256) void k_eout(
    const bf16* __restrict__ ein, const int* __restrict__ etype,
    const float* __restrict__ Wec, const float* __restrict__ bec,
    float* __restrict__ eout, int nE)
{
  int wid  = (blockIdx.x*blockDim.x + threadIdx.x) >> 6;
  int lane = threadIdx.x & 63;
  if (wid >= nE) return;
  int t = etype[wid];
  float v = fmaxf(b2f(ein[(size_t)wid*64 + lane]), 0.f);
  float p = wred(v * Wec[t*64 + lane]);
  if (lane==0) eout[wid] = p + bec[t];
}

extern "C" void kernel_launch(void* const* d_in, const int* in_sizes, int n_in,
                              void* d_out, int out_size, void* d_ws, size_t ws_size,
                              hipStream_t stream) {
  const float* x      = (const float*)d_in[0];
  const int*   eidx   = (const int*) d_in[1];
  const int*   ntype  = (const int*) d_in[2];
  const int*   etype  = (const int*) d_in[3];
  const float* eattr  = (const float*)d_in[4];
  const float* Whl[3]  = {(const float*)d_in[5],  (const float*)d_in[11], (const float*)d_in[17]};
  const float* bhl[3]  = {(const float*)d_in[6],  (const float*)d_in[12], (const float*)d_in[18]};
  const float* Ete[3]  = {(const float*)d_in[7],  (const float*)d_in[13], (const float*)d_in[19]};
  const float* Wea[3]  = {(const float*)d_in[8],  (const float*)d_in[14], (const float*)d_in[20]};
  const float* Watt[3] = {(const float*)d_in[9],  (const float*)d_in[15], (const float*)d_in[21]};
  const float* Wlin[3] = {(const float*)d_in[10], (const float*)d_in[16], (const float*)d_in[22]};
  const float* Wnc = (const float*)d_in[23];
  const float* bnc = (const float*)d_in[24];
  const float* Wec = (const float*)d_in[25];
  const float* bec = (const float*)d_in[26];

  const int nN = in_sizes[2];      // 50000
  const int nE = in_sizes[3];      // 800000
  const int* srcI = eidx;
  const int* dstI = eidx + nE;

  // workspace layout (f32 words)
  float* ws = (float*)d_ws;
  size_t o = 0;
  bf16*  h      = (bf16*)(ws + o); o += (size_t)nN*32;   // [N][64] bf16
  float* outA   = ws + o;                                 // [N][64] f32, ALIASES uv below
  bf16*  uv     = (bf16*)(ws + o); o += (size_t)nN*64;   // [N][128] bf16 (same bytes as outA)
  float* hi_s   = ws + o;          o += (size_t)nN;
  float* hj_s   = ws + o;          o += (size_t)nN;
  float* exbuf  = ws + o;          o += (size_t)nE;      // logits -> exp
  float* segsum = ws + o;          o += (size_t)nN;
  bf16*  ea     = (bf16*)(ws + o); o += (size_t)nE*32;   // [E][64] bf16, in-place across layers
  int*   deg    = (int*)(ws + o);  o += (size_t)nN;
  int*   off    = (int*)(ws + o);  o += (size_t)nN + 1;
  int*   eid    = (int*)(ws + o);  o += (size_t)nE;

  dim3 blk(256);
  int nodeWB = (int)(((size_t)nN*64 + 255)/256);   // wave-per-node
  int edgeWB = (int)(((size_t)nE*64 + 255)/256);   // wave-per-edge
  int edgeTB = (nE + 255)/256;                     // thread-per-edge
  int nodeTB = (nN + 255)/256;                     // thread-per-node

  // ---- CSR build (once; dst is layer-invariant) ----
  hipMemsetAsync(deg, 0, (size_t)nN*4, stream);
  k_hist<<<edgeTB, blk, 0, stream>>>(dstI, deg, nE);
  k_scan<<<1, 1024, 0, stream>>>(deg, off, nN);
  hipMemsetAsync(deg, 0, (size_t)nN*4, stream);          // reuse as scatter counter
  k_scatter<<<edgeTB, blk, 0, stream>>>(dstI, off, deg, eid, nE);

  for (int L = 0; L < 3; ++L) {
    if (L == 0)
      k_hlin<float,false><<<nodeWB, blk, 0, stream>>>(x,    ntype, Whl[L], bhl[L], Watt[L], h, hi_s, hj_s, nN);
    else
      k_hlin<float,true ><<<nodeWB, blk, 0, stream>>>(outA, ntype, Whl[L], bhl[L], Watt[L], h, hi_s, hj_s, nN);

    if (L == 0)
      k_ea<float,false,32><<<edgeWB, blk, 0, stream>>>(eattr, Wea[L], Watt[L], ea, exbuf, nE);
    else
      k_ea<bf16 ,true ,64><<<edgeWB, blk, 0, stream>>>(ea,    Wea[L], Watt[L], ea, exbuf, nE);

    hipMemsetAsync(segsum, 0, (size_t)nN*4, stream);
    k_att<<<edgeTB, blk, 0, stream>>>(srcI, dstI, etype, Ete[L], Watt[L], hi_s, hj_s, exbuf, segsum, nE);
    k_inv<<<nodeTB, blk, 0, stream>>>(segsum, nN);

    k_agg<<<nodeWB, blk, 0, stream>>>(off, eid, srcI, h, ea, exbuf, segsum, uv, nN);
    k_mm <<<nodeWB, blk, 0, stream>>>(uv, Wlin[L], outA, nN);
  }

  float* xout = (float*)d_out;
  k_xout<<<nodeWB, blk, 0, stream>>>(outA, ntype, Wnc, bnc, xout, nN);
  k_eout<<<edgeWB, blk, 0, stream>>>(ea,   etype, Wec, bec, xout + nN, nE);
}

// Round 8
// 1394.737 us; speedup vs baseline: 7.1057x; 1.9300x over previous
//
#include <hip/hip_runtime.h>
#include <hip/hip_bf16.h>

#define NEG 0.2f
#define LRELU(x) ((x) > 0.f ? (x) : NEG*(x))

typedef __hip_bfloat16 bf16;
typedef __attribute__((ext_vector_type(8))) short short8v;  // 8 bf16 (4 VGPRs)
typedef __attribute__((ext_vector_type(4))) float f32x4;

__device__ __forceinline__ float b2f(bf16 v){ return __bfloat162float(v); }
__device__ __forceinline__ float ldf(const float* p, size_t i){ return p[i]; }
__device__ __forceinline__ float ldf(const bf16* p, size_t i){ return __bfloat162float(p[i]); }

__device__ __forceinline__ float wred(float v){
#pragma unroll
  for(int o=32;o>0;o>>=1) v += __shfl_down(v,o);
  return v; // valid at lane 0
}

__device__ __forceinline__ float atomAddF(float* p, float v){
  return __hip_atomic_fetch_add(p, v, __ATOMIC_RELAXED, __HIP_MEMORY_SCOPE_AGENT);
}
__device__ __forceinline__ int atomAddI(int* p, int v){
  return __hip_atomic_fetch_add(p, v, __ATOMIC_RELAXED, __HIP_MEMORY_SCOPE_AGENT);
}

// ---------------- CSR build (dst is layer-invariant; built once per call) ----------------

__global__ __launch_bounds__(256) void k_hist(
    const int* __restrict__ dst, int* __restrict__ deg, int nE)
{
  int e = blockIdx.x*blockDim.x + threadIdx.x;
  if (e >= nE) return;
  atomAddI(&deg[dst[e]], 1);
}

__global__ __launch_bounds__(1024) void k_scan(
    const int* __restrict__ deg, int* __restrict__ off, int nN)
{
  __shared__ int part[1024];
  int tid = threadIdx.x;
  int chunk = (nN + 1023) / 1024;
  int lo = tid*chunk, hi = min((tid+1)*chunk, nN);
  int s = 0;
  for (int i=lo;i<hi;i++) s += deg[i];
  part[tid] = s;
  __syncthreads();
  for (int d=1; d<1024; d<<=1){
    int v = (tid>=d) ? part[tid-d] : 0;
    __syncthreads();
    part[tid] += v;
    __syncthreads();
  }
  int run = (tid==0) ? 0 : part[tid-1];
  for (int i=lo;i<hi;i++){ off[i] = run; run += deg[i]; }
  if (tid==1023) off[nN] = part[1023];
}

__global__ __launch_bounds__(256) void k_scatter(
    const int* __restrict__ dst, const int* __restrict__ off,
    int* __restrict__ cnt, int* __restrict__ eid, int nE)
{
  int e = blockIdx.x*blockDim.x + threadIdx.x;
  if (e >= nE) return;
  int d = dst[e];
  int p = atomAddI(&cnt[d], 1);
  eid[off[d] + p] = e;
}

// ---------------- per-layer kernels ----------------

// h[n,:] = (relu?)xin[n,:] @ Whl[t[n]] + bhl[t[n]]   (bf16 out, f32 accum)
// also hi_s[n]=h·Watt[0:64], hj_s[n]=h·Watt[64:128]
template<typename TIN, bool RELU_IN>
__global__ __launch_bounds__(256) void k_hlin(
    const TIN* __restrict__ xin, const int* __restrict__ ntype,
    const float* __restrict__ Whl, const float* __restrict__ bhl,
    const float* __restrict__ Watt,
    bf16* __restrict__ h, float* __restrict__ hi_s, float* __restrict__ hj_s,
    int nN)
{
  int wid  = (blockIdx.x*blockDim.x + threadIdx.x) >> 6;
  int lane = threadIdx.x & 63;
  if (wid >= nN) return;
  int t = ntype[wid];
  float xv = ldf(xin, (size_t)wid*64 + lane);
  if (RELU_IN) xv = fmaxf(xv, 0.f);
  const float* W = Whl + (size_t)t*4096;
  float acc = bhl[t*64 + lane];
#pragma unroll
  for (int i=0;i<64;i++) acc = fmaf(__shfl(xv, i), W[i*64 + lane], acc);
  h[(size_t)wid*64 + lane] = __float2bfloat16(acc);
  float pi = wred(acc * Watt[lane]);
  float pj = wred(acc * Watt[64 + lane]);
  if (lane==0){ hi_s[wid]=pi; hj_s[wid]=pj; }
}

// Build B fragments for mfma_f32_16x16x32_bf16 from f32 W [KS*32][64]:
// frag[nt][ks][lane][j] = bf16(W[ks*32 + (lane>>4)*8 + j][nt*16 + (lane&15)])
__global__ __launch_bounds__(512) void k_bfrag(
    const float* __restrict__ W, bf16* __restrict__ frag, int KS)
{
  int t = blockIdx.x*blockDim.x + threadIdx.x;
  int total = 4*KS*64;
  if (t >= total) return;
  int lane = t & 63;
  int ks = (t>>6) % KS;
  int nt = (t>>6) / KS;
  int kb = lane>>4, col = lane&15;
#pragma unroll
  for (int j=0;j<8;j++){
    frag[((size_t)(nt*KS+ks)*64 + lane)*8 + j] =
      __float2bfloat16(W[(ks*32 + kb*8 + j)*64 + nt*16 + col]);
  }
}

// MFMA edge transform: one wave per 16 edges.
// eout[e,:] = lrelu((relu?)ain[e,:] @ W)  (bf16 out; in-place safe — rows read fully first)
// logits[e] = lrelu'd f32 acc · Watt[132:196]
template<bool L0>
__global__ __launch_bounds__(256) void k_ea_mfma(
    const void* __restrict__ ain_, const bf16* __restrict__ bfrag,
    const float* __restrict__ Watt,
    bf16* __restrict__ eout, float* __restrict__ logits, int nE)
{
  constexpr int KS = L0 ? 1 : 2;
  int wid  = (blockIdx.x*blockDim.x + threadIdx.x) >> 6;
  int lane = threadIdx.x & 63;
  int e0 = wid * 16;
  if (e0 >= nE) return;
  int row = lane & 15;     // A-row / D-col within tile
  int kb  = lane >> 4;     // 0..3
  int er  = min(e0 + row, nE-1);

  // ---- A fragments: lane holds A[row][kb*8+j] per K-step ----
  short8v a[KS];
  if (L0) {
    const float* A = (const float*)ain_;
    const float* p = A + (size_t)er*32 + kb*8;
#pragma unroll
    for (int j=0;j<8;j++){
      bf16 b = __float2bfloat16(p[j]);
      a[0][j] = *reinterpret_cast<short*>(&b);
    }
  } else {
    const bf16* A = (const bf16*)ain_;
#pragma unroll
    for (int ks=0; ks<KS; ks++){
      short8v v = *reinterpret_cast<const short8v*>(
          reinterpret_cast<const short*>(A + (size_t)er*64 + ks*32 + kb*8));
      // relu on packed bf16: negative iff sign bit set
#pragma unroll
      for (int j=0;j<8;j++) v[j] = (v[j] & (short)0x8000) ? (short)0 : v[j];
      a[ks] = v;
    }
  }

  // ---- 4 N-tiles x KS K-steps of mfma ----
  f32x4 acc[4];
#pragma unroll
  for (int nt=0; nt<4; nt++){
    f32x4 c = {0.f,0.f,0.f,0.f};
#pragma unroll
    for (int ks=0; ks<KS; ks++){
      short8v b = *reinterpret_cast<const short8v*>(
          reinterpret_cast<const short*>(bfrag) + (((size_t)nt*KS + ks)*64 + lane)*8);
      c = __builtin_amdgcn_mfma_f32_16x16x32_bf16(a[ks], b, c, 0, 0, 0);
    }
#pragma unroll
    for (int r=0;r<4;r++) c[r] = LRELU(c[r]);
    acc[nt] = c;
  }

  // ---- store eout: D col=lane&15, row=kb*4+r (m89-verified) ----
#pragma unroll
  for (int r=0;r<4;r++){
    int e = e0 + kb*4 + r;
    if (e < nE){
#pragma unroll
      for (int nt=0;nt<4;nt++)
        eout[(size_t)e*64 + nt*16 + row] = __float2bfloat16(acc[nt][r]);
    }
  }

  // ---- logits: dot with Watt[132:196], reduce over the 16-lane col group ----
#pragma unroll
  for (int r=0;r<4;r++){
    float part = 0.f;
#pragma unroll
    for (int nt=0;nt<4;nt++) part = fmaf(acc[nt][r], Watt[132 + nt*16 + row], part);
#pragma unroll
    for (int m=1;m<16;m<<=1) part += __shfl_xor(part, m);
    int e = e0 + kb*4 + r;
    if (row == 0 && e < nE) logits[e] = part;
  }
}

// fused: l = lrelu(partial + hi_s[dst] + hj_s[src] + lrelu(Ete[et])·Watt[128:132])
//        ex = exp(min(l,60)); logits[e]=ex; segsum[dst]+=ex
__global__ __launch_bounds__(256) void k_att(
    const int* __restrict__ src, const int* __restrict__ dst,
    const int* __restrict__ etype, const float* __restrict__ Ete,
    const float* __restrict__ Watt,
    const float* __restrict__ hi_s, const float* __restrict__ hj_s,
    float* __restrict__ logits, float* __restrict__ segsum, int nE)
{
  int e = blockIdx.x*blockDim.x + threadIdx.x;
  if (e >= nE) return;
  int d = dst[e], s = src[e], t = etype[e];
  float wt = 0.f;
#pragma unroll
  for (int k=0;k<4;k++){ float v = Ete[t*4+k]; v = LRELU(v); wt = fmaf(v, Watt[128+k], wt); }
  float l = logits[e] + hi_s[d] + hj_s[s] + wt;
  l = LRELU(l);
  float ex = __expf(fminf(l, 60.f));
  logits[e] = ex;
  atomAddF(&segsum[d], ex);
}

// segsum[n] := 1/(segsum[n]+1e-16)
__global__ __launch_bounds__(256) void k_inv(float* __restrict__ segsum, int nN)
{
  int n = blockIdx.x*blockDim.x + threadIdx.x;
  if (n >= nN) return;
  segsum[n] = 1.f / (segsum[n] + 1e-16f);
}

// CSR aggregation: u[n]=Σ α h[src], v[n]=Σ α ea[e]  → uv[n][0:64]=u, uv[n][64:128]=v (bf16)
__global__ __launch_bounds__(256) void k_agg(
    const int* __restrict__ off, const int* __restrict__ eid,
    const int* __restrict__ src,
    const bf16* __restrict__ h, const bf16* __restrict__ ea,
    const float* __restrict__ ex, const float* __restrict__ inv_segsum,
    bf16* __restrict__ uv, int nN)
{
  int wid  = (blockIdx.x*blockDim.x + threadIdx.x) >> 6;
  int lane = threadIdx.x & 63;
  if (wid >= nN) return;
  int beg = off[wid], end = off[wid+1];
  float inv = inv_segsum[wid];
  float au = 0.f, av = 0.f;
  int i = beg;
  int eC = 0, sC = 0; float aC = 0.f;
  if (i < end){ eC = eid[i]; sC = src[eC]; aC = ex[eC]; }
  while (i < end){
    int e = eC, s = sC; float a = aC * inv;
    int j = i + 1;
    if (j < end){ eC = eid[j]; sC = src[eC]; aC = ex[eC]; }
    float hv = b2f(h[(size_t)s*64 + lane]);
    float ev = b2f(ea[(size_t)e*64 + lane]);
    au = fmaf(a, hv, au);
    av = fmaf(a, ev, av);
    i = j;
  }
  uv[(size_t)wid*128 + lane]      = __float2bfloat16(au);
  uv[(size_t)wid*128 + 64 + lane] = __float2bfloat16(av);
}

// out[n] = u@Wlin[:64] + v@Wlin[64:]; out (f32) aliases uv (bf16) — wave-local read-before-write
__global__ __launch_bounds__(256) void k_mm(
    const bf16* uv, const float* __restrict__ Wlin, float* out, int nN)
{
  int wid  = (blockIdx.x*blockDim.x + threadIdx.x) >> 6;
  int lane = threadIdx.x & 63;
  if (wid >= nN) return;
  float u0 = b2f(uv[(size_t)wid*128 + lane]);
  float u1 = b2f(uv[(size_t)wid*128 + 64 + lane]);
  float acc = 0.f;
#pragma unroll
  for (int k=0;k<64;k++) acc = fmaf(__shfl(u0,k), Wlin[k*64 + lane], acc);
#pragma unroll
  for (int k=0;k<64;k++) acc = fmaf(__shfl(u1,k), Wlin[(64+k)*64 + lane], acc);
  out[(size_t)wid*64 + lane] = acc;
}

// x_out[n] = relu(outA[n])·Wnc[t] + bnc[t]   (f32 out)
__global__ __launch_bounds__(256) void k_xout(
    const float* __restrict__ hin, const int* __restrict__ ntype,
    const float* __restrict__ Wnc, const float* __restrict__ bnc,
    float* __restrict__ xout, int nN)
{
  int wid  = (blockIdx.x*blockDim.x + threadIdx.x) >> 6;
  int lane = threadIdx.x & 63;
  if (wid >= nN) return;
  int t = ntype[wid];
  float v = fmaxf(hin[(size_t)wid*64 + lane], 0.f);
  float p = wred(v * Wnc[t*64 + lane]);
  if (lane==0) xout[wid] = p + bnc[t];
}

// e_out[e] = relu(ea[e])·Wec[t] + bec[t]   (f32 out)
__global__ __launch_bounds__(256) void k_eout(
    const bf16* __restrict__ ein, const int* __restrict__ etype,
    const float* __restrict__ Wec, const float* __restrict__ bec,
    float* __restrict__ eout, int nE)
{
  int wid  = (blockIdx.x*blockDim.x + threadIdx.x) >> 6;
  int lane = threadIdx.x & 63;
  if (wid >= nE) return;
  int t = etype[wid];
  float v = fmaxf(b2f(ein[(size_t)wid*64 + lane]), 0.f);
  float p = wred(v * Wec[t*64 + lane]);
  if (lane==0) eout[wid] = p + bec[t];
}

extern "C" void kernel_launch(void* const* d_in, const int* in_sizes, int n_in,
                              void* d_out, int out_size, void* d_ws, size_t ws_size,
                              hipStream_t stream) {
  const float* x      = (const float*)d_in[0];
  const int*   eidx   = (const int*) d_in[1];
  const int*   ntype  = (const int*) d_in[2];
  const int*   etype  = (const int*) d_in[3];
  const float* eattr  = (const float*)d_in[4];
  const float* Whl[3]  = {(const float*)d_in[5],  (const float*)d_in[11], (const float*)d_in[17]};
  const float* bhl[3]  = {(const float*)d_in[6],  (const float*)d_in[12], (const float*)d_in[18]};
  const float* Ete[3]  = {(const float*)d_in[7],  (const float*)d_in[13], (const float*)d_in[19]};
  const float* Wea[3]  = {(const float*)d_in[8],  (const float*)d_in[14], (const float*)d_in[20]};
  const float* Watt[3] = {(const float*)d_in[9],  (const float*)d_in[15], (const float*)d_in[21]};
  const float* Wlin[3] = {(const float*)d_in[10], (const float*)d_in[16], (const float*)d_in[22]};
  const float* Wnc = (const float*)d_in[23];
  const float* bnc = (const float*)d_in[24];
  const float* Wec = (const float*)d_in[25];
  const float* bec = (const float*)d_in[26];

  const int nN = in_sizes[2];      // 50000
  const int nE = in_sizes[3];      // 800000
  const int* srcI = eidx;
  const int* dstI = eidx + nE;

  // workspace layout (f32 words)
  float* ws = (float*)d_ws;
  size_t o = 0;
  bf16*  h      = (bf16*)(ws + o); o += (size_t)nN*32;   // [N][64] bf16
  float* outA   = ws + o;                                 // [N][64] f32, ALIASES uv below
  bf16*  uv     = (bf16*)(ws + o); o += (size_t)nN*64;   // [N][128] bf16 (same bytes as outA)
  float* hi_s   = ws + o;          o += (size_t)nN;
  float* hj_s   = ws + o;          o += (size_t)nN;
  float* exbuf  = ws + o;          o += (size_t)nE;      // logits -> exp
  float* segsum = ws + o;          o += (size_t)nN;
  bf16*  ea     = (bf16*)(ws + o); o += (size_t)nE*32;   // [E][64] bf16, in-place across layers
  int*   deg    = (int*)(ws + o);  o += (size_t)nN;
  int*   off    = (int*)(ws + o);  o += (size_t)nN + 1;
  int*   eid    = (int*)(ws + o);  o += (size_t)nE;
  o = (o + 3) & ~(size_t)3;                              // 16B align
  bf16*  bfrag  = (bf16*)(ws + o); o += (size_t)4096/2;  // 4*2*64*8 bf16 = 8KB

  dim3 blk(256);
  int nodeWB = (int)(((size_t)nN*64 + 255)/256);   // wave-per-node
  int edgeWB = (int)(((size_t)nE*64 + 255)/256);   // wave-per-edge
  int edgeTB = (nE + 255)/256;                     // thread-per-edge
  int nodeTB = (nN + 255)/256;                     // thread-per-node
  int eaMB   = (int)(((size_t)((nE+15)/16)*64 + 255)/256); // wave-per-16-edges

  // ---- CSR build (once; dst is layer-invariant) ----
  hipMemsetAsync(deg, 0, (size_t)nN*4, stream);
  k_hist<<<edgeTB, blk, 0, stream>>>(dstI, deg, nE);
  k_scan<<<1, 1024, 0, stream>>>(deg, off, nN);
  hipMemsetAsync(deg, 0, (size_t)nN*4, stream);
  k_scatter<<<edgeTB, blk, 0, stream>>>(dstI, off, deg, eid, nE);

  for (int L = 0; L < 3; ++L) {
    if (L == 0)
      k_hlin<float,false><<<nodeWB, blk, 0, stream>>>(x,    ntype, Whl[L], bhl[L], Watt[L], h, hi_s, hj_s, nN);
    else
      k_hlin<float,true ><<<nodeWB, blk, 0, stream>>>(outA, ntype, Whl[L], bhl[L], Watt[L], h, hi_s, hj_s, nN);

    // ---- edge transform via MFMA ----
    int KS = (L==0) ? 1 : 2;
    k_bfrag<<<1, 4*KS*64, 0, stream>>>(Wea[L], bfrag, KS);
    if (L == 0)
      k_ea_mfma<true ><<<eaMB, blk, 0, stream>>>(eattr, bfrag, Watt[L], ea, exbuf, nE);
    else
      k_ea_mfma<false><<<eaMB, blk, 0, stream>>>(ea,    bfrag, Watt[L], ea, exbuf, nE);

    hipMemsetAsync(segsum, 0, (size_t)nN*4, stream);
    k_att<<<edgeTB, blk, 0, stream>>>(srcI, dstI, etype, Ete[L], Watt[L], hi_s, hj_s, exbuf, segsum, nE);
    k_inv<<<nodeTB, blk, 0, stream>>>(segsum, nN);

    k_agg<<<nodeWB, blk, 0, stream>>>(off, eid, srcI, h, ea, exbuf, segsum, uv, nN);
    k_mm <<<nodeWB, blk, 0, stream>>>(uv, Wlin[L], outA, nN);
  }

  float* xout = (float*)d_out;
  k_xout<<<nodeWB, blk, 0, stream>>>(outA, ntype, Wnc, bnc, xout, nN);
  k_eout<<<edgeWB, blk, 0, stream>>>(ea,   etype, Wec, bec, xout + nN, nE);
}

// Round 9
// 1052.925 us; speedup vs baseline: 9.4125x; 1.3246x over previous
//
#include <hip/hip_runtime.h>
#include <hip/hip_bf16.h>

#define NEG 0.2f
#define LRELU(x) ((x) > 0.f ? (x) : NEG*(x))

typedef __hip_bfloat16 bf16;
typedef __attribute__((ext_vector_type(8))) short short8v;  // 8 bf16 (4 VGPRs)
typedef __attribute__((ext_vector_type(4))) float f32x4;

__device__ __forceinline__ float b2f(bf16 v){ return __bfloat162float(v); }
__device__ __forceinline__ float ldf(const float* p, size_t i){ return p[i]; }
__device__ __forceinline__ float ldf(const bf16* p, size_t i){ return __bfloat162float(p[i]); }

__device__ __forceinline__ float wred(float v){
#pragma unroll
  for(int o=32;o>0;o>>=1) v += __shfl_down(v,o);
  return v; // valid at lane 0
}

__device__ __forceinline__ float atomAddF(float* p, float v){
  return __hip_atomic_fetch_add(p, v, __ATOMIC_RELAXED, __HIP_MEMORY_SCOPE_AGENT);
}
__device__ __forceinline__ int atomAddI(int* p, int v){
  return __hip_atomic_fetch_add(p, v, __ATOMIC_RELAXED, __HIP_MEMORY_SCOPE_AGENT);
}

// ---------------- CSR build (dst is layer-invariant; built once per call) ----------------

__global__ __launch_bounds__(256) void k_hist(
    const int* __restrict__ dst, int* __restrict__ deg, int nE)
{
  int e = blockIdx.x*blockDim.x + threadIdx.x;
  if (e >= nE) return;
  atomAddI(&deg[dst[e]], 1);
}

__global__ __launch_bounds__(1024) void k_scan(
    const int* __restrict__ deg, int* __restrict__ off, int nN)
{
  __shared__ int part[1024];
  int tid = threadIdx.x;
  int chunk = (nN + 1023) / 1024;
  int lo = tid*chunk, hi = min((tid+1)*chunk, nN);
  int s = 0;
  for (int i=lo;i<hi;i++) s += deg[i];
  part[tid] = s;
  __syncthreads();
  for (int d=1; d<1024; d<<=1){
    int v = (tid>=d) ? part[tid-d] : 0;
    __syncthreads();
    part[tid] += v;
    __syncthreads();
  }
  int run = (tid==0) ? 0 : part[tid-1];
  for (int i=lo;i<hi;i++){ off[i] = run; run += deg[i]; }
  if (tid==1023) off[nN] = part[1023];
}

__global__ __launch_bounds__(256) void k_scatter(
    const int* __restrict__ dst, const int* __restrict__ off,
    int* __restrict__ cnt, int* __restrict__ eid, int nE)
{
  int e = blockIdx.x*blockDim.x + threadIdx.x;
  if (e >= nE) return;
  int d = dst[e];
  int p = atomAddI(&cnt[d], 1);
  eid[off[d] + p] = e;
}

// ---------------- per-layer kernels ----------------

// h[n,:] = (relu?)xin[n,:] @ Whl[t[n]] + bhl[t[n]]   (bf16 out, f32 accum)
// also hi_s[n]=h·Watt[0:64], hj_s[n]=h·Watt[64:128]
template<typename TIN, bool RELU_IN>
__global__ __launch_bounds__(256) void k_hlin(
    const TIN* __restrict__ xin, const int* __restrict__ ntype,
    const float* __restrict__ Whl, const float* __restrict__ bhl,
    const float* __restrict__ Watt,
    bf16* __restrict__ h, float* __restrict__ hi_s, float* __restrict__ hj_s,
    int nN)
{
  int wid  = (blockIdx.x*blockDim.x + threadIdx.x) >> 6;
  int lane = threadIdx.x & 63;
  if (wid >= nN) return;
  int t = ntype[wid];
  float xv = ldf(xin, (size_t)wid*64 + lane);
  if (RELU_IN) xv = fmaxf(xv, 0.f);
  const float* W = Whl + (size_t)t*4096;
  float acc = bhl[t*64 + lane];
#pragma unroll
  for (int i=0;i<64;i++) acc = fmaf(__shfl(xv, i), W[i*64 + lane], acc);
  h[(size_t)wid*64 + lane] = __float2bfloat16(acc);
  float pi = wred(acc * Watt[lane]);
  float pj = wred(acc * Watt[64 + lane]);
  if (lane==0){ hi_s[wid]=pi; hj_s[wid]=pj; }
}

// Build B fragments for mfma_f32_16x16x32_bf16 from f32 W [KS*32][64]:
// frag[nt][ks][lane][j] = bf16(W[ks*32 + (lane>>4)*8 + j][nt*16 + (lane&15)])
__global__ __launch_bounds__(256) void k_bfrag(
    const float* __restrict__ W, bf16* __restrict__ frag, int KS)
{
  int t = blockIdx.x*blockDim.x + threadIdx.x;
  int total = 4*KS*64;
  if (t >= total) return;
  int lane = t & 63;
  int ks = (t>>6) % KS;
  int nt = (t>>6) / KS;
  int kb = lane>>4, col = lane&15;
#pragma unroll
  for (int j=0;j<8;j++){
    frag[((size_t)(nt*KS+ks)*64 + lane)*8 + j] =
      __float2bfloat16(W[(ks*32 + kb*8 + j)*64 + nt*16 + col]);
  }
}

// MFMA edge transform + FUSED attention epilogue. One wave per 16 edges.
// eout[e,:] = lrelu((relu?)ain[e,:] @ Wea)  (bf16; in-place safe — lockstep read-before-write)
// exbuf[e]  = exp(lrelu(full_logit));  segsum[dst[e]] += exbuf[e]
// LAYER==2: e_out[e] = relu(acc)·Wec[etype[e]] + bec[etype[e]]
template<int LAYER>
__global__ __launch_bounds__(256) void k_ea_mfma(
    const void* __restrict__ ain_, const bf16* __restrict__ bfrag,
    const float* __restrict__ Watt,
    const int* __restrict__ src, const int* __restrict__ dst,
    const int* __restrict__ etype, const float* __restrict__ Ete,
    const float* __restrict__ hi_s, const float* __restrict__ hj_s,
    bf16* __restrict__ eout, float* __restrict__ exbuf, float* __restrict__ segsum,
    const float* __restrict__ Wec, const float* __restrict__ bec,
    float* __restrict__ e_out, int nE)
{
  constexpr int KS = (LAYER==0) ? 1 : 2;
  int wid  = (blockIdx.x*blockDim.x + threadIdx.x) >> 6;
  int lane = threadIdx.x & 63;
  int e0 = wid * 16;
  if (e0 >= nE) return;
  int row = lane & 15;     // A-row (load) / D-col (store) within tile
  int kb  = lane >> 4;     // 0..3
  int er  = min(e0 + row, nE-1);

  // ---- A fragments ----
  short8v a[KS];
  if (LAYER==0) {
    const float* A = (const float*)ain_;
    const float* p = A + (size_t)er*32 + kb*8;
#pragma unroll
    for (int j=0;j<8;j++){
      bf16 b = __float2bfloat16(p[j]);
      a[0][j] = *reinterpret_cast<short*>(&b);
    }
  } else {
    const bf16* A = (const bf16*)ain_;
#pragma unroll
    for (int ks=0; ks<KS; ks++){
      short8v v = *reinterpret_cast<const short8v*>(
          reinterpret_cast<const short*>(A + (size_t)er*64 + ks*32 + kb*8));
#pragma unroll
      for (int j=0;j<8;j++) v[j] = (v[j] & (short)0x8000) ? (short)0 : v[j];
      a[ks] = v;
    }
  }

  // ---- 4 N-tiles x KS K-steps of mfma ----
  f32x4 acc[4];
#pragma unroll
  for (int nt=0; nt<4; nt++){
    f32x4 c = {0.f,0.f,0.f,0.f};
#pragma unroll
    for (int ks=0; ks<KS; ks++){
      short8v b = *reinterpret_cast<const short8v*>(
          reinterpret_cast<const short*>(bfrag) + (((size_t)nt*KS + ks)*64 + lane)*8);
      c = __builtin_amdgcn_mfma_f32_16x16x32_bf16(a[ks], b, c, 0, 0, 0);
    }
#pragma unroll
    for (int r=0;r<4;r++) c[r] = LRELU(c[r]);
    acc[nt] = c;
  }

  // ---- store eout: D col=lane&15, row=kb*4+r ----
#pragma unroll
  for (int r=0;r<4;r++){
    int e = e0 + kb*4 + r;
    if (e < nE){
#pragma unroll
      for (int nt=0;nt<4;nt++)
        eout[(size_t)e*64 + nt*16 + row] = __float2bfloat16(acc[nt][r]);
    }
  }

  // ---- fused epilogue: logits + attention (+ e_out for LAYER==2) ----
#pragma unroll
  for (int r=0;r<4;r++){
    int e = e0 + kb*4 + r;           // same e for all 16 lanes of group kb
    bool valid = (e < nE);
    int t = valid ? etype[e] : 0;    // broadcast load within group
    float lp = 0.f, pe = 0.f;
#pragma unroll
    for (int nt=0;nt<4;nt++) lp = fmaf(acc[nt][r], Watt[132 + nt*16 + row], lp);
    if (LAYER==2){
#pragma unroll
      for (int nt=0;nt<4;nt++) pe = fmaf(fmaxf(acc[nt][r],0.f), Wec[t*64 + nt*16 + row], pe);
    }
#pragma unroll
    for (int m=1;m<16;m<<=1){
      lp += __shfl_xor(lp, m);
      if (LAYER==2) pe += __shfl_xor(pe, m);
    }
    if (row == 0 && valid){
      int d = dst[e], s = src[e];
      float wt = 0.f;
#pragma unroll
      for (int k=0;k<4;k++){ float v = Ete[t*4+k]; v = LRELU(v); wt = fmaf(v, Watt[128+k], wt); }
      float l = lp + hi_s[d] + hj_s[s] + wt;
      l = LRELU(l);
      float ex = __expf(fminf(l, 60.f));
      exbuf[e] = ex;
      atomAddF(&segsum[d], ex);
      if (LAYER==2) e_out[e] = pe + bec[t];
    }
  }
}

// segsum[n] := 1/(segsum[n]+1e-16)
__global__ __launch_bounds__(256) void k_inv(float* __restrict__ segsum, int nN)
{
  int n = blockIdx.x*blockDim.x + threadIdx.x;
  if (n >= nN) return;
  segsum[n] = 1.f / (segsum[n] + 1e-16f);
}

// CSR aggregation: u[n]=Σ α h[src], v[n]=Σ α ea[e]  → uv[n][0:64]=u, uv[n][64:128]=v (bf16)
__global__ __launch_bounds__(256) void k_agg(
    const int* __restrict__ off, const int* __restrict__ eid,
    const int* __restrict__ src,
    const bf16* __restrict__ h, const bf16* __restrict__ ea,
    const float* __restrict__ ex, const float* __restrict__ inv_segsum,
    bf16* __restrict__ uv, int nN)
{
  int wid  = (blockIdx.x*blockDim.x + threadIdx.x) >> 6;
  int lane = threadIdx.x & 63;
  if (wid >= nN) return;
  int beg = off[wid], end = off[wid+1];
  float inv = inv_segsum[wid];
  float au = 0.f, av = 0.f;
  int i = beg;
  int eC = 0, sC = 0; float aC = 0.f;
  if (i < end){ eC = eid[i]; sC = src[eC]; aC = ex[eC]; }
  while (i < end){
    int e = eC, s = sC; float a = aC * inv;
    int j = i + 1;
    if (j < end){ eC = eid[j]; sC = src[eC]; aC = ex[eC]; }
    float hv = b2f(h[(size_t)s*64 + lane]);
    float ev = b2f(ea[(size_t)e*64 + lane]);
    au = fmaf(a, hv, au);
    av = fmaf(a, ev, av);
    i = j;
  }
  uv[(size_t)wid*128 + lane]      = __float2bfloat16(au);
  uv[(size_t)wid*128 + 64 + lane] = __float2bfloat16(av);
}

// MFMA node matmul: out[n] = uv[n,0:128] @ Wlin[128][64]. One wave per 16 nodes.
// out (f32) aliases uv (bf16): safe — wave-lockstep, all A-loads waited before MFMA, stores after.
__global__ __launch_bounds__(256) void k_mm_mfma(
    const bf16* __restrict__ uv, const bf16* __restrict__ bfrag,
    float* __restrict__ out, int nN)
{
  int wid  = (blockIdx.x*blockDim.x + threadIdx.x) >> 6;
  int lane = threadIdx.x & 63;
  int n0 = wid * 16;
  if (n0 >= nN) return;
  int row = lane & 15;
  int kb  = lane >> 4;
  int nr  = min(n0 + row, nN-1);

  short8v a[4];
#pragma unroll
  for (int ks=0; ks<4; ks++)
    a[ks] = *reinterpret_cast<const short8v*>(
        reinterpret_cast<const short*>(uv + (size_t)nr*128 + ks*32 + kb*8));

  f32x4 acc[4];
#pragma unroll
  for (int nt=0; nt<4; nt++){
    f32x4 c = {0.f,0.f,0.f,0.f};
#pragma unroll
    for (int ks=0; ks<4; ks++){
      short8v b = *reinterpret_cast<const short8v*>(
          reinterpret_cast<const short*>(bfrag) + (((size_t)nt*4 + ks)*64 + lane)*8);
      c = __builtin_amdgcn_mfma_f32_16x16x32_bf16(a[ks], b, c, 0, 0, 0);
    }
    acc[nt] = c;
  }

#pragma unroll
  for (int r=0;r<4;r++){
    int n = n0 + kb*4 + r;
    if (n < nN){
#pragma unroll
      for (int nt=0;nt<4;nt++)
        out[(size_t)n*64 + nt*16 + row] = acc[nt][r];
    }
  }
}

// x_out[n] = relu(outA[n])·Wnc[t] + bnc[t]   (f32 out)
__global__ __launch_bounds__(256) void k_xout(
    const float* __restrict__ hin, const int* __restrict__ ntype,
    const float* __restrict__ Wnc, const float* __restrict__ bnc,
    float* __restrict__ xout, int nN)
{
  int wid  = (blockIdx.x*blockDim.x + threadIdx.x) >> 6;
  int lane = threadIdx.x & 63;
  if (wid >= nN) return;
  int t = ntype[wid];
  float v = fmaxf(hin[(size_t)wid*64 + lane], 0.f);
  float p = wred(v * Wnc[t*64 + lane]);
  if (lane==0) xout[wid] = p + bnc[t];
}

extern "C" void kernel_launch(void* const* d_in, const int* in_sizes, int n_in,
                              void* d_out, int out_size, void* d_ws, size_t ws_size,
                              hipStream_t stream) {
  const float* x      = (const float*)d_in[0];
  const int*   eidx   = (const int*) d_in[1];
  const int*   ntype  = (const int*) d_in[2];
  const int*   etype  = (const int*) d_in[3];
  const float* eattr  = (const float*)d_in[4];
  const float* Whl[3]  = {(const float*)d_in[5],  (const float*)d_in[11], (const float*)d_in[17]};
  const float* bhl[3]  = {(const float*)d_in[6],  (const float*)d_in[12], (const float*)d_in[18]};
  const float* Ete[3]  = {(const float*)d_in[7],  (const float*)d_in[13], (const float*)d_in[19]};
  const float* Wea[3]  = {(const float*)d_in[8],  (const float*)d_in[14], (const float*)d_in[20]};
  const float* Watt[3] = {(const float*)d_in[9],  (const float*)d_in[15], (const float*)d_in[21]};
  const float* Wlin[3] = {(const float*)d_in[10], (const float*)d_in[16], (const float*)d_in[22]};
  const float* Wnc = (const float*)d_in[23];
  const float* bnc = (const float*)d_in[24];
  const float* Wec = (const float*)d_in[25];
  const float* bec = (const float*)d_in[26];

  const int nN = in_sizes[2];      // 50000
  const int nE = in_sizes[3];      // 800000
  const int* srcI = eidx;
  const int* dstI = eidx + nE;

  // workspace layout (f32 words)
  float* ws = (float*)d_ws;
  size_t o = 0;
  bf16*  h      = (bf16*)(ws + o); o += (size_t)nN*32;   // [N][64] bf16
  float* outA   = ws + o;                                 // [N][64] f32, ALIASES uv below
  bf16*  uv     = (bf16*)(ws + o); o += (size_t)nN*64;   // [N][128] bf16 (same bytes as outA)
  float* hi_s   = ws + o;          o += (size_t)nN;
  float* hj_s   = ws + o;          o += (size_t)nN;
  float* exbuf  = ws + o;          o += (size_t)nE;      // exp(logit)
  float* segsum = ws + o;          o += (size_t)nN;
  bf16*  ea     = (bf16*)(ws + o); o += (size_t)nE*32;   // [E][64] bf16, in-place across layers
  int*   deg    = (int*)(ws + o);  o += (size_t)nN;
  int*   off    = (int*)(ws + o);  o += (size_t)nN + 1;
  int*   eid    = (int*)(ws + o);  o += (size_t)nE;
  o = (o + 3) & ~(size_t)3;                              // 16B align
  bf16*  bfrag  = (bf16*)(ws + o); o += (size_t)4096;    // up to 4nt*4ks*64*8 bf16 = 16KB

  dim3 blk(256);
  int nodeWB = (int)(((size_t)nN*64 + 255)/256);   // wave-per-node
  int edgeTB = (nE + 255)/256;                     // thread-per-edge
  int nodeTB = (nN + 255)/256;                     // thread-per-node
  int eaMB   = (int)(((size_t)((nE+15)/16)*64 + 255)/256); // wave per 16 edges
  int mmMB   = (int)(((size_t)((nN+15)/16)*64 + 255)/256); // wave per 16 nodes

  // ---- CSR build (once; dst is layer-invariant) ----
  hipMemsetAsync(deg, 0, (size_t)nN*4, stream);
  k_hist<<<edgeTB, blk, 0, stream>>>(dstI, deg, nE);
  k_scan<<<1, 1024, 0, stream>>>(deg, off, nN);
  hipMemsetAsync(deg, 0, (size_t)nN*4, stream);
  k_scatter<<<edgeTB, blk, 0, stream>>>(dstI, off, deg, eid, nE);

  float* xout = (float*)d_out;

  for (int L = 0; L < 3; ++L) {
    if (L == 0)
      k_hlin<float,false><<<nodeWB, blk, 0, stream>>>(x,    ntype, Whl[L], bhl[L], Watt[L], h, hi_s, hj_s, nN);
    else
      k_hlin<float,true ><<<nodeWB, blk, 0, stream>>>(outA, ntype, Whl[L], bhl[L], Watt[L], h, hi_s, hj_s, nN);

    hipMemsetAsync(segsum, 0, (size_t)nN*4, stream);

    int KS = (L==0) ? 1 : 2;
    k_bfrag<<<(4*KS*64 + 255)/256, blk, 0, stream>>>(Wea[L], bfrag, KS);
    if (L == 0)
      k_ea_mfma<0><<<eaMB, blk, 0, stream>>>(eattr, bfrag, Watt[L], srcI, dstI, etype, Ete[L],
                                             hi_s, hj_s, ea, exbuf, segsum, nullptr, nullptr, nullptr, nE);
    else if (L == 1)
      k_ea_mfma<1><<<eaMB, blk, 0, stream>>>(ea, bfrag, Watt[L], srcI, dstI, etype, Ete[L],
                                             hi_s, hj_s, ea, exbuf, segsum, nullptr, nullptr, nullptr, nE);
    else
      k_ea_mfma<2><<<eaMB, blk, 0, stream>>>(ea, bfrag, Watt[L], srcI, dstI, etype, Ete[L],
                                             hi_s, hj_s, ea, exbuf, segsum, Wec, bec, xout + nN, nE);

    k_inv<<<nodeTB, blk, 0, stream>>>(segsum, nN);
    k_agg<<<nodeWB, blk, 0, stream>>>(off, eid, srcI, h, ea, exbuf, segsum, uv, nN);

    k_bfrag<<<(4*4*64 + 255)/256, blk, 0, stream>>>(Wlin[L], bfrag, 4);
    k_mm_mfma<<<mmMB, blk, 0, stream>>>(uv, bfrag, outA, nN);
  }

  k_xout<<<nodeWB, blk, 0, stream>>>(outA, ntype, Wnc, bnc, xout, nN);
}

// Round 10
// 928.589 us; speedup vs baseline: 10.6728x; 1.1339x over previous
//
#include <hip/hip_runtime.h>
#include <hip/hip_bf16.h>

#define NEG 0.2f
#define LRELU(x) ((x) > 0.f ? (x) : NEG*(x))

typedef __hip_bfloat16 bf16;
typedef __attribute__((ext_vector_type(8))) short short8v;  // 8 bf16 (4 VGPRs)
typedef __attribute__((ext_vector_type(4))) float f32x4;

__device__ __forceinline__ float b2f(bf16 v){ return __bfloat162float(v); }
__device__ __forceinline__ float ldf(const float* p, size_t i){ return p[i]; }
__device__ __forceinline__ float ldf(const bf16* p, size_t i){ return __bfloat162float(p[i]); }

__device__ __forceinline__ float wred(float v){
#pragma unroll
  for(int o=32;o>0;o>>=1) v += __shfl_down(v,o);
  return v; // valid at lane 0
}

__device__ __forceinline__ int atomAddI(int* p, int v){
  return __hip_atomic_fetch_add(p, v, __ATOMIC_RELAXED, __HIP_MEMORY_SCOPE_AGENT);
}

// ---------------- CSR build (dst is layer-invariant; built once per call) ----------------

__global__ __launch_bounds__(256) void k_hist(
    const int* __restrict__ dst, int* __restrict__ deg, int nE)
{
  int e = blockIdx.x*blockDim.x + threadIdx.x;
  if (e >= nE) return;
  atomAddI(&deg[dst[e]], 1);
}

__global__ __launch_bounds__(1024) void k_scan(
    const int* __restrict__ deg, int* __restrict__ off, int nN)
{
  __shared__ int part[1024];
  int tid = threadIdx.x;
  int chunk = (nN + 1023) / 1024;
  int lo = tid*chunk, hi = min((tid+1)*chunk, nN);
  int s = 0;
  for (int i=lo;i<hi;i++) s += deg[i];
  part[tid] = s;
  __syncthreads();
  for (int d=1; d<1024; d<<=1){
    int v = (tid>=d) ? part[tid-d] : 0;
    __syncthreads();
    part[tid] += v;
    __syncthreads();
  }
  int run = (tid==0) ? 0 : part[tid-1];
  for (int i=lo;i<hi;i++){ off[i] = run; run += deg[i]; }
  if (tid==1023) off[nN] = part[1023];
}

__global__ __launch_bounds__(256) void k_scatter(
    const int* __restrict__ dst, const int* __restrict__ off,
    int* __restrict__ cnt, int* __restrict__ eid, int nE)
{
  int e = blockIdx.x*blockDim.x + threadIdx.x;
  if (e >= nE) return;
  int d = dst[e];
  int p = atomAddI(&cnt[d], 1);
  eid[off[d] + p] = e;
}

// sorted copies of src/dst/etype (one-time)
__global__ __launch_bounds__(256) void k_perm(
    const int* __restrict__ eid, const int* __restrict__ src,
    const int* __restrict__ dst, const int* __restrict__ ety,
    int* __restrict__ srcP, int* __restrict__ dstP, int* __restrict__ etyP, int nE)
{
  int i = blockIdx.x*blockDim.x + threadIdx.x;
  if (i >= nE) return;
  int e = eid[i];
  srcP[i] = src[e];
  dstP[i] = dst[e];
  etyP[i] = ety[e];
}

// ---------------- per-layer kernels ----------------

// h[n,:] = (relu?)xin[n,:] @ Whl[t[n]] + bhl[t[n]]   (bf16 out, f32 accum)
// also hi_s[n]=h·Watt[0:64], hj_s[n]=h·Watt[64:128]
template<typename TIN, bool RELU_IN>
__global__ __launch_bounds__(256) void k_hlin(
    const TIN* __restrict__ xin, const int* __restrict__ ntype,
    const float* __restrict__ Whl, const float* __restrict__ bhl,
    const float* __restrict__ Watt,
    bf16* __restrict__ h, float* __restrict__ hi_s, float* __restrict__ hj_s,
    int nN)
{
  int wid  = (blockIdx.x*blockDim.x + threadIdx.x) >> 6;
  int lane = threadIdx.x & 63;
  if (wid >= nN) return;
  int t = ntype[wid];
  float xv = ldf(xin, (size_t)wid*64 + lane);
  if (RELU_IN) xv = fmaxf(xv, 0.f);
  const float* W = Whl + (size_t)t*4096;
  float acc = bhl[t*64 + lane];
#pragma unroll
  for (int i=0;i<64;i++) acc = fmaf(__shfl(xv, i), W[i*64 + lane], acc);
  h[(size_t)wid*64 + lane] = __float2bfloat16(acc);
  float pi = wred(acc * Watt[lane]);
  float pj = wred(acc * Watt[64 + lane]);
  if (lane==0){ hi_s[wid]=pi; hj_s[wid]=pj; }
}

// Build B fragments for mfma_f32_16x16x32_bf16 from f32 W [KS*32][64]:
// frag[nt][ks][lane][j] = bf16(W[ks*32 + (lane>>4)*8 + j][nt*16 + (lane&15)])
__global__ __launch_bounds__(256) void k_bfrag(
    const float* __restrict__ W, bf16* __restrict__ frag, int KS)
{
  int t = blockIdx.x*blockDim.x + threadIdx.x;
  int total = 4*KS*64;
  if (t >= total) return;
  int lane = t & 63;
  int ks = (t>>6) % KS;
  int nt = (t>>6) / KS;
  int kb = lane>>4, col = lane&15;
#pragma unroll
  for (int j=0;j<8;j++){
    frag[((size_t)(nt*KS+ks)*64 + lane)*8 + j] =
      __float2bfloat16(W[(ks*32 + kb*8 + j)*64 + nt*16 + col]);
  }
}

// MFMA edge transform + fused attention epilogue, on DST-SORTED edge storage.
// Row i of eaS corresponds to original edge eid[i].
// eaS[i,:] = lrelu((relu?)ain[i,:] @ Wea); exS[i] = exp(lrelu(full_logit))
// LAYER==0: A-rows gathered from eattr[eid[i]].  LAYER==2: e_out[eid[i]] = relu(acc)·Wec+bec
template<int LAYER>
__global__ __launch_bounds__(256) void k_ea_mfma(
    const void* __restrict__ ain_, const int* __restrict__ eid,
    const bf16* __restrict__ bfrag, const float* __restrict__ Watt,
    const int* __restrict__ srcP, const int* __restrict__ dstP,
    const int* __restrict__ etyP, const float* __restrict__ Ete,
    const float* __restrict__ hi_s, const float* __restrict__ hj_s,
    bf16* __restrict__ eaS, float* __restrict__ exS,
    const float* __restrict__ Wec, const float* __restrict__ bec,
    float* __restrict__ e_out, int nE)
{
  constexpr int KS = (LAYER==0) ? 1 : 2;
  int wid  = (blockIdx.x*blockDim.x + threadIdx.x) >> 6;
  int lane = threadIdx.x & 63;
  int e0 = wid * 16;
  if (e0 >= nE) return;
  int row = lane & 15;     // A-row (load) / D-col (store) within tile
  int kb  = lane >> 4;     // 0..3
  int er  = min(e0 + row, nE-1);

  // ---- A fragments ----
  short8v a[KS];
  if (LAYER==0) {
    const float* A = (const float*)ain_;
    const float* p = A + (size_t)eid[er]*32 + kb*8;   // gather original edge_attr row
#pragma unroll
    for (int j=0;j<8;j++){
      bf16 b = __float2bfloat16(p[j]);
      a[0][j] = *reinterpret_cast<short*>(&b);
    }
  } else {
    const bf16* A = (const bf16*)ain_;                // sequential sorted rows
#pragma unroll
    for (int ks=0; ks<KS; ks++){
      short8v v = *reinterpret_cast<const short8v*>(
          reinterpret_cast<const short*>(A + (size_t)er*64 + ks*32 + kb*8));
#pragma unroll
      for (int j=0;j<8;j++) v[j] = (v[j] & (short)0x8000) ? (short)0 : v[j];
      a[ks] = v;
    }
  }

  // ---- 4 N-tiles x KS K-steps of mfma ----
  f32x4 acc[4];
#pragma unroll
  for (int nt=0; nt<4; nt++){
    f32x4 c = {0.f,0.f,0.f,0.f};
#pragma unroll
    for (int ks=0; ks<KS; ks++){
      short8v b = *reinterpret_cast<const short8v*>(
          reinterpret_cast<const short*>(bfrag) + (((size_t)nt*KS + ks)*64 + lane)*8);
      c = __builtin_amdgcn_mfma_f32_16x16x32_bf16(a[ks], b, c, 0, 0, 0);
    }
#pragma unroll
    for (int r=0;r<4;r++) c[r] = LRELU(c[r]);
    acc[nt] = c;
  }

  // ---- store eaS: D col=lane&15, row=kb*4+r ----
#pragma unroll
  for (int r=0;r<4;r++){
    int e = e0 + kb*4 + r;
    if (e < nE){
#pragma unroll
      for (int nt=0;nt<4;nt++)
        eaS[(size_t)e*64 + nt*16 + row] = __float2bfloat16(acc[nt][r]);
    }
  }

  // ---- fused epilogue: logits (+ e_out for LAYER==2), no atomics ----
#pragma unroll
  for (int r=0;r<4;r++){
    int e = e0 + kb*4 + r;           // same e for all 16 lanes of group kb
    bool valid = (e < nE);
    int t = valid ? etyP[e] : 0;
    float lp = 0.f, pe = 0.f;
#pragma unroll
    for (int nt=0;nt<4;nt++) lp = fmaf(acc[nt][r], Watt[132 + nt*16 + row], lp);
    if (LAYER==2){
#pragma unroll
      for (int nt=0;nt<4;nt++) pe = fmaf(fmaxf(acc[nt][r],0.f), Wec[t*64 + nt*16 + row], pe);
    }
#pragma unroll
    for (int m=1;m<16;m<<=1){
      lp += __shfl_xor(lp, m);
      if (LAYER==2) pe += __shfl_xor(pe, m);
    }
    if (row == 0 && valid){
      int d = dstP[e], s = srcP[e];
      float wt = 0.f;
#pragma unroll
      for (int k=0;k<4;k++){ float v = Ete[t*4+k]; v = LRELU(v); wt = fmaf(v, Watt[128+k], wt); }
      float l = lp + hi_s[d] + hj_s[s] + wt;
      l = LRELU(l);
      exS[e] = __expf(fminf(l, 60.f));
      if (LAYER==2) e_out[eid[e]] = pe + bec[t];
    }
  }
}

// Streaming CSR aggregation (sorted edges): node wid owns rows off[wid]..off[wid+1].
// ss=Σex; u=Σ ex·h[src]; v=Σ ex·ea  → uv = {u,v}/ss   (softmax normalization folded in)
__global__ __launch_bounds__(256) void k_agg(
    const int* __restrict__ off, const int* __restrict__ srcP,
    const bf16* __restrict__ h, const bf16* __restrict__ eaS,
    const float* __restrict__ exS,
    bf16* __restrict__ uv, int nN)
{
  int wid  = (blockIdx.x*blockDim.x + threadIdx.x) >> 6;
  int lane = threadIdx.x & 63;
  if (wid >= nN) return;
  int beg = off[wid], end = off[wid+1];
  float au = 0.f, av = 0.f, ss = 0.f;
  int i = beg;
  int sC = 0; float aC = 0.f;
  if (i < end){ sC = srcP[i]; aC = exS[i]; }
  while (i < end){
    int s = sC; float a = aC;
    int j = i + 1;
    if (j < end){ sC = srcP[j]; aC = exS[j]; }   // prefetch next edge scalars
    float hv = b2f(h[(size_t)s*64 + lane]);      // random row gather (L2/L3-resident)
    float ev = b2f(eaS[(size_t)i*64 + lane]);    // sequential
    au = fmaf(a, hv, au);
    av = fmaf(a, ev, av);
    ss += a;
    i = j;
  }
  float inv = 1.f / (ss + 1e-16f);
  uv[(size_t)wid*128 + lane]      = __float2bfloat16(au * inv);
  uv[(size_t)wid*128 + 64 + lane] = __float2bfloat16(av * inv);
}

// MFMA node matmul: out[n] = uv[n,0:128] @ Wlin[128][64]. One wave per 16 nodes.
// out (f32) aliases uv (bf16): safe — wave-lockstep, loads waited before MFMA, stores after.
__global__ __launch_bounds__(256) void k_mm_mfma(
    const bf16* __restrict__ uv, const bf16* __restrict__ bfrag,
    float* __restrict__ out, int nN)
{
  int wid  = (blockIdx.x*blockDim.x + threadIdx.x) >> 6;
  int lane = threadIdx.x & 63;
  int n0 = wid * 16;
  if (n0 >= nN) return;
  int row = lane & 15;
  int kb  = lane >> 4;
  int nr  = min(n0 + row, nN-1);

  short8v a[4];
#pragma unroll
  for (int ks=0; ks<4; ks++)
    a[ks] = *reinterpret_cast<const short8v*>(
        reinterpret_cast<const short*>(uv + (size_t)nr*128 + ks*32 + kb*8));

  f32x4 acc[4];
#pragma unroll
  for (int nt=0; nt<4; nt++){
    f32x4 c = {0.f,0.f,0.f,0.f};
#pragma unroll
    for (int ks=0; ks<4; ks++){
      short8v b = *reinterpret_cast<const short8v*>(
          reinterpret_cast<const short*>(bfrag) + (((size_t)nt*4 + ks)*64 + lane)*8);
      c = __builtin_amdgcn_mfma_f32_16x16x32_bf16(a[ks], b, c, 0, 0, 0);
    }
    acc[nt] = c;
  }

#pragma unroll
  for (int r=0;r<4;r++){
    int n = n0 + kb*4 + r;
    if (n < nN){
#pragma unroll
      for (int nt=0;nt<4;nt++)
        out[(size_t)n*64 + nt*16 + row] = acc[nt][r];
    }
  }
}

// x_out[n] = relu(outA[n])·Wnc[t] + bnc[t]   (f32 out)
__global__ __launch_bounds__(256) void k_xout(
    const float* __restrict__ hin, const int* __restrict__ ntype,
    const float* __restrict__ Wnc, const float* __restrict__ bnc,
    float* __restrict__ xout, int nN)
{
  int wid  = (blockIdx.x*blockDim.x + threadIdx.x) >> 6;
  int lane = threadIdx.x & 63;
  if (wid >= nN) return;
  int t = ntype[wid];
  float v = fmaxf(hin[(size_t)wid*64 + lane], 0.f);
  float p = wred(v * Wnc[t*64 + lane]);
  if (lane==0) xout[wid] = p + bnc[t];
}

extern "C" void kernel_launch(void* const* d_in, const int* in_sizes, int n_in,
                              void* d_out, int out_size, void* d_ws, size_t ws_size,
                              hipStream_t stream) {
  const float* x      = (const float*)d_in[0];
  const int*   eidx   = (const int*) d_in[1];
  const int*   ntype  = (const int*) d_in[2];
  const int*   etype  = (const int*) d_in[3];
  const float* eattr  = (const float*)d_in[4];
  const float* Whl[3]  = {(const float*)d_in[5],  (const float*)d_in[11], (const float*)d_in[17]};
  const float* bhl[3]  = {(const float*)d_in[6],  (const float*)d_in[12], (const float*)d_in[18]};
  const float* Ete[3]  = {(const float*)d_in[7],  (const float*)d_in[13], (const float*)d_in[19]};
  const float* Wea[3]  = {(const float*)d_in[8],  (const float*)d_in[14], (const float*)d_in[20]};
  const float* Watt[3] = {(const float*)d_in[9],  (const float*)d_in[15], (const float*)d_in[21]};
  const float* Wlin[3] = {(const float*)d_in[10], (const float*)d_in[16], (const float*)d_in[22]};
  const float* Wnc = (const float*)d_in[23];
  const float* bnc = (const float*)d_in[24];
  const float* Wec = (const float*)d_in[25];
  const float* bec = (const float*)d_in[26];

  const int nN = in_sizes[2];      // 50000
  const int nE = in_sizes[3];      // 800000
  const int* srcI = eidx;
  const int* dstI = eidx + nE;

  // workspace layout (f32 words)
  float* ws = (float*)d_ws;
  size_t o = 0;
  bf16*  h      = (bf16*)(ws + o); o += (size_t)nN*32;   // [N][64] bf16
  float* outA   = ws + o;                                 // [N][64] f32, ALIASES uv below
  bf16*  uv     = (bf16*)(ws + o); o += (size_t)nN*64;   // [N][128] bf16 (same bytes as outA)
  float* hi_s   = ws + o;          o += (size_t)nN;
  float* hj_s   = ws + o;          o += (size_t)nN;
  float* exS    = ws + o;          o += (size_t)nE;      // exp(logit), sorted order
  bf16*  eaS    = (bf16*)(ws + o); o += (size_t)nE*32;   // [E][64] bf16, SORTED, in-place across layers
  int*   deg    = (int*)(ws + o);  o += (size_t)nN;
  int*   off    = (int*)(ws + o);  o += (size_t)nN + 1;
  int*   eid    = (int*)(ws + o);  o += (size_t)nE;
  int*   srcP   = (int*)(ws + o);  o += (size_t)nE;
  int*   dstP   = (int*)(ws + o);  o += (size_t)nE;
  int*   etyP   = (int*)(ws + o);  o += (size_t)nE;
  o = (o + 3) & ~(size_t)3;                              // 16B align
  bf16*  bfrag  = (bf16*)(ws + o); o += (size_t)4096;    // up to 4nt*4ks*64*8 bf16 = 16KB

  dim3 blk(256);
  int nodeWB = (int)(((size_t)nN*64 + 255)/256);   // wave-per-node
  int edgeTB = (nE + 255)/256;                     // thread-per-edge
  int eaMB   = (int)(((size_t)((nE+15)/16)*64 + 255)/256); // wave per 16 edges
  int mmMB   = (int)(((size_t)((nN+15)/16)*64 + 255)/256); // wave per 16 nodes

  // ---- CSR build + permuted index arrays (once; dst is layer-invariant) ----
  hipMemsetAsync(deg, 0, (size_t)nN*4, stream);
  k_hist<<<edgeTB, blk, 0, stream>>>(dstI, deg, nE);
  k_scan<<<1, 1024, 0, stream>>>(deg, off, nN);
  hipMemsetAsync(deg, 0, (size_t)nN*4, stream);
  k_scatter<<<edgeTB, blk, 0, stream>>>(dstI, off, deg, eid, nE);
  k_perm<<<edgeTB, blk, 0, stream>>>(eid, srcI, dstI, etype, srcP, dstP, etyP, nE);

  float* xout = (float*)d_out;

  for (int L = 0; L < 3; ++L) {
    if (L == 0)
      k_hlin<float,false><<<nodeWB, blk, 0, stream>>>(x,    ntype, Whl[L], bhl[L], Watt[L], h, hi_s, hj_s, nN);
    else
      k_hlin<float,true ><<<nodeWB, blk, 0, stream>>>(outA, ntype, Whl[L], bhl[L], Watt[L], h, hi_s, hj_s, nN);

    int KS = (L==0) ? 1 : 2;
    k_bfrag<<<(4*KS*64 + 255)/256, blk, 0, stream>>>(Wea[L], bfrag, KS);
    if (L == 0)
      k_ea_mfma<0><<<eaMB, blk, 0, stream>>>(eattr, eid, bfrag, Watt[L], srcP, dstP, etyP, Ete[L],
                                             hi_s, hj_s, eaS, exS, nullptr, nullptr, nullptr, nE);
    else if (L == 1)
      k_ea_mfma<1><<<eaMB, blk, 0, stream>>>(eaS, eid, bfrag, Watt[L], srcP, dstP, etyP, Ete[L],
                                             hi_s, hj_s, eaS, exS, nullptr, nullptr, nullptr, nE);
    else
      k_ea_mfma<2><<<eaMB, blk, 0, stream>>>(eaS, eid, bfrag, Watt[L], srcP, dstP, etyP, Ete[L],
                                             hi_s, hj_s, eaS, exS, Wec, bec, xout + nN, nE);

    k_agg<<<nodeWB, blk, 0, stream>>>(off, srcP, h, eaS, exS, uv, nN);

    k_bfrag<<<(4*4*64 + 255)/256, blk, 0, stream>>>(Wlin[L], bfrag, 4);
    k_mm_mfma<<<mmMB, blk, 0, stream>>>(uv, bfrag, outA, nN);
  }

  k_xout<<<nodeWB, blk, 0, stream>>>(outA, ntype, Wnc, bnc, xout, nN);
}

// Round 11
// 913.052 us; speedup vs baseline: 10.8544x; 1.0170x over previous
//
#include <hip/hip_runtime.h>
#include <hip/hip_bf16.h>

#define NEG 0.2f
#define LRELU(x) ((x) > 0.f ? (x) : NEG*(x))

typedef __hip_bfloat16 bf16;
typedef __attribute__((ext_vector_type(8))) short short8v;  // 8 bf16 (4 VGPRs)
typedef __attribute__((ext_vector_type(4))) float f32x4;

__device__ __forceinline__ float b2f(bf16 v){ return __bfloat162float(v); }
__device__ __forceinline__ float ldf(const float* p, size_t i){ return p[i]; }
__device__ __forceinline__ float ldf(const bf16* p, size_t i){ return __bfloat162float(p[i]); }

__device__ __forceinline__ float wred(float v){
#pragma unroll
  for(int o=32;o>0;o>>=1) v += __shfl_down(v,o);
  return v; // valid at lane 0
}

__device__ __forceinline__ int atomAddI(int* p, int v){
  return __hip_atomic_fetch_add(p, v, __ATOMIC_RELAXED, __HIP_MEMORY_SCOPE_AGENT);
}

// ---------------- CSR build (dst is layer-invariant; built once per call) ----------------

__global__ __launch_bounds__(256) void k_hist(
    const int* __restrict__ dst, int* __restrict__ deg, int nE)
{
  int e = blockIdx.x*blockDim.x + threadIdx.x;
  if (e >= nE) return;
  atomAddI(&deg[dst[e]], 1);
}

__global__ __launch_bounds__(1024) void k_scan(
    const int* __restrict__ deg, int* __restrict__ off, int nN)
{
  __shared__ int part[1024];
  int tid = threadIdx.x;
  int chunk = (nN + 1023) / 1024;
  int lo = tid*chunk, hi = min((tid+1)*chunk, nN);
  int s = 0;
  for (int i=lo;i<hi;i++) s += deg[i];
  part[tid] = s;
  __syncthreads();
  for (int d=1; d<1024; d<<=1){
    int v = (tid>=d) ? part[tid-d] : 0;
    __syncthreads();
    part[tid] += v;
    __syncthreads();
  }
  int run = (tid==0) ? 0 : part[tid-1];
  for (int i=lo;i<hi;i++){ off[i] = run; run += deg[i]; }
  if (tid==1023) off[nN] = part[1023];
}

__global__ __launch_bounds__(256) void k_scatter(
    const int* __restrict__ dst, const int* __restrict__ off,
    int* __restrict__ cnt, int* __restrict__ eid, int nE)
{
  int e = blockIdx.x*blockDim.x + threadIdx.x;
  if (e >= nE) return;
  int d = dst[e];
  int p = atomAddI(&cnt[d], 1);
  eid[off[d] + p] = e;
}

// sorted copies of src/dst/etype (one-time)
__global__ __launch_bounds__(256) void k_perm(
    const int* __restrict__ eid, const int* __restrict__ src,
    const int* __restrict__ dst, const int* __restrict__ ety,
    int* __restrict__ srcP, int* __restrict__ dstP, int* __restrict__ etyP, int nE)
{
  int i = blockIdx.x*blockDim.x + threadIdx.x;
  if (i >= nE) return;
  int e = eid[i];
  srcP[i] = src[e];
  dstP[i] = dst[e];
  etyP[i] = ety[e];
}

// ---------------- per-layer kernels ----------------

// h[n,:] = (relu?)xin[n,:] @ Whl[t[n]] + bhl[t[n]]   (bf16 out, f32 accum)
// also hi_s[n]=h·Watt[0:64], hj_s[n]=h·Watt[64:128]
template<typename TIN, bool RELU_IN>
__global__ __launch_bounds__(256) void k_hlin(
    const TIN* __restrict__ xin, const int* __restrict__ ntype,
    const float* __restrict__ Whl, const float* __restrict__ bhl,
    const float* __restrict__ Watt,
    bf16* __restrict__ h, float* __restrict__ hi_s, float* __restrict__ hj_s,
    int nN)
{
  int wid  = (blockIdx.x*blockDim.x + threadIdx.x) >> 6;
  int lane = threadIdx.x & 63;
  if (wid >= nN) return;
  int t = ntype[wid];
  float xv = ldf(xin, (size_t)wid*64 + lane);
  if (RELU_IN) xv = fmaxf(xv, 0.f);
  const float* W = Whl + (size_t)t*4096;
  float acc = bhl[t*64 + lane];
#pragma unroll
  for (int i=0;i<64;i++) acc = fmaf(__shfl(xv, i), W[i*64 + lane], acc);
  h[(size_t)wid*64 + lane] = __float2bfloat16(acc);
  float pi = wred(acc * Watt[lane]);
  float pj = wred(acc * Watt[64 + lane]);
  if (lane==0){ hi_s[wid]=pi; hj_s[wid]=pj; }
}

// Build B fragments for mfma_f32_16x16x32_bf16 from f32 W [KS*32][64]:
// frag[nt][ks][lane][j] = bf16(W[ks*32 + (lane>>4)*8 + j][nt*16 + (lane&15)])
__global__ __launch_bounds__(256) void k_bfrag(
    const float* __restrict__ W, bf16* __restrict__ frag, int KS)
{
  int t = blockIdx.x*blockDim.x + threadIdx.x;
  int total = 4*KS*64;
  if (t >= total) return;
  int lane = t & 63;
  int ks = (t>>6) % KS;
  int nt = (t>>6) / KS;
  int kb = lane>>4, col = lane&15;
#pragma unroll
  for (int j=0;j<8;j++){
    frag[((size_t)(nt*KS+ks)*64 + lane)*8 + j] =
      __float2bfloat16(W[(ks*32 + kb*8 + j)*64 + nt*16 + col]);
  }
}

// MFMA edge transform + fused attention epilogue, DST-SORTED storage, 32 edges per wave
// (2 independent 16-edge tiles for latency hiding; B-frags reused across tiles).
template<int LAYER>
__global__ __launch_bounds__(256) void k_ea_mfma(
    const void* __restrict__ ain_, const int* __restrict__ eid,
    const bf16* __restrict__ bfrag, const float* __restrict__ Watt,
    const int* __restrict__ srcP, const int* __restrict__ dstP,
    const int* __restrict__ etyP, const float* __restrict__ Ete,
    const float* __restrict__ hi_s, const float* __restrict__ hj_s,
    bf16* __restrict__ eaS, float* __restrict__ exS,
    const float* __restrict__ Wec, const float* __restrict__ bec,
    float* __restrict__ e_out, int nE)
{
  constexpr int KS = (LAYER==0) ? 1 : 2;
  int wid  = (blockIdx.x*blockDim.x + threadIdx.x) >> 6;
  int lane = threadIdx.x & 63;
  int e0 = wid * 32;
  if (e0 >= nE) return;
  int row = lane & 15;
  int kb  = lane >> 4;

  // ---- A fragments for both tiles ----
  short8v a[2][KS];
#pragma unroll
  for (int tl=0; tl<2; tl++){
    int er = min(e0 + tl*16 + row, nE-1);
    if (LAYER==0) {
      const float* A = (const float*)ain_;
      const float* p = A + (size_t)eid[er]*32 + kb*8;
#pragma unroll
      for (int j=0;j<8;j++){
        bf16 b = __float2bfloat16(p[j]);
        a[tl][0][j] = *reinterpret_cast<short*>(&b);
      }
    } else {
      const bf16* A = (const bf16*)ain_;
#pragma unroll
      for (int ks=0; ks<KS; ks++){
        short8v v = *reinterpret_cast<const short8v*>(
            reinterpret_cast<const short*>(A + (size_t)er*64 + ks*32 + kb*8));
#pragma unroll
        for (int j=0;j<8;j++) v[j] = (v[j] & (short)0x8000) ? (short)0 : v[j];
        a[tl][ks] = v;
      }
    }
  }

  // ---- MFMAs: 4 N-tiles x KS K-steps x 2 edge-tiles (B loaded once per nt/ks) ----
  f32x4 acc[2][4];
#pragma unroll
  for (int nt=0; nt<4; nt++){
    f32x4 c0 = {0.f,0.f,0.f,0.f}, c1 = {0.f,0.f,0.f,0.f};
#pragma unroll
    for (int ks=0; ks<KS; ks++){
      short8v b = *reinterpret_cast<const short8v*>(
          reinterpret_cast<const short*>(bfrag) + (((size_t)nt*KS + ks)*64 + lane)*8);
      c0 = __builtin_amdgcn_mfma_f32_16x16x32_bf16(a[0][ks], b, c0, 0, 0, 0);
      c1 = __builtin_amdgcn_mfma_f32_16x16x32_bf16(a[1][ks], b, c1, 0, 0, 0);
    }
#pragma unroll
    for (int r=0;r<4;r++){ c0[r] = LRELU(c0[r]); c1[r] = LRELU(c1[r]); }
    acc[0][nt] = c0; acc[1][nt] = c1;
  }

  // ---- store eaS ----
#pragma unroll
  for (int tl=0; tl<2; tl++){
#pragma unroll
    for (int r=0;r<4;r++){
      int e = e0 + tl*16 + kb*4 + r;
      if (e < nE){
#pragma unroll
        for (int nt=0;nt<4;nt++)
          eaS[(size_t)e*64 + nt*16 + row] = __float2bfloat16(acc[tl][nt][r]);
      }
    }
  }

  // ---- fused epilogue (both tiles interleaved for ILP) ----
#pragma unroll
  for (int tl=0; tl<2; tl++){
#pragma unroll
    for (int r=0;r<4;r++){
      int e = e0 + tl*16 + kb*4 + r;
      bool valid = (e < nE);
      int t = valid ? etyP[e] : 0;
      float lp = 0.f, pe = 0.f;
#pragma unroll
      for (int nt=0;nt<4;nt++) lp = fmaf(acc[tl][nt][r], Watt[132 + nt*16 + row], lp);
      if (LAYER==2){
#pragma unroll
        for (int nt=0;nt<4;nt++) pe = fmaf(fmaxf(acc[tl][nt][r],0.f), Wec[t*64 + nt*16 + row], pe);
      }
#pragma unroll
      for (int m=1;m<16;m<<=1){
        lp += __shfl_xor(lp, m);
        if (LAYER==2) pe += __shfl_xor(pe, m);
      }
      if (row == 0 && valid){
        int d = dstP[e], s = srcP[e];
        float wt = 0.f;
#pragma unroll
        for (int k=0;k<4;k++){ float v = Ete[t*4+k]; v = LRELU(v); wt = fmaf(v, Watt[128+k], wt); }
        float l = lp + hi_s[d] + hj_s[s] + wt;
        l = LRELU(l);
        exS[e] = __expf(fminf(l, 60.f));
        if (LAYER==2) e_out[eid[e]] = pe + bec[t];
      }
    }
  }
}

// Streaming CSR aggregation (sorted edges), 2 edges per iteration for load ILP.
__global__ __launch_bounds__(256) void k_agg(
    const int* __restrict__ off, const int* __restrict__ srcP,
    const bf16* __restrict__ h, const bf16* __restrict__ eaS,
    const float* __restrict__ exS,
    bf16* __restrict__ uv, int nN)
{
  int wid  = (blockIdx.x*blockDim.x + threadIdx.x) >> 6;
  int lane = threadIdx.x & 63;
  if (wid >= nN) return;
  int beg = off[wid], end = off[wid+1];
  float au = 0.f, av = 0.f, ss = 0.f;
  int i = beg;
  for (; i+1 < end; i += 2){
    int   s0 = srcP[i],   s1 = srcP[i+1];
    float a0 = exS[i],    a1 = exS[i+1];
    float h0 = b2f(h[(size_t)s0*64 + lane]);
    float h1 = b2f(h[(size_t)s1*64 + lane]);
    float v0 = b2f(eaS[(size_t)i*64 + lane]);
    float v1 = b2f(eaS[(size_t)(i+1)*64 + lane]);
    au = fmaf(a0, h0, au); av = fmaf(a0, v0, av); ss += a0;
    au = fmaf(a1, h1, au); av = fmaf(a1, v1, av); ss += a1;
  }
  if (i < end){
    int s = srcP[i]; float a = exS[i];
    au = fmaf(a, b2f(h[(size_t)s*64 + lane]), au);
    av = fmaf(a, b2f(eaS[(size_t)i*64 + lane]), av);
    ss += a;
  }
  float inv = 1.f / (ss + 1e-16f);
  uv[(size_t)wid*128 + lane]      = __float2bfloat16(au * inv);
  uv[(size_t)wid*128 + 64 + lane] = __float2bfloat16(av * inv);
}

// MFMA node matmul: out[n] = uv[n,0:128] @ Wlin. FINAL: fuse x_out = relu(out)·Wnc[t]+bnc[t].
template<bool FINAL>
__global__ __launch_bounds__(256) void k_mm_mfma(
    const bf16* __restrict__ uv, const bf16* __restrict__ bfrag,
    float* __restrict__ out,
    const int* __restrict__ ntype, const float* __restrict__ Wnc,
    const float* __restrict__ bnc, float* __restrict__ xout, int nN)
{
  int wid  = (blockIdx.x*blockDim.x + threadIdx.x) >> 6;
  int lane = threadIdx.x & 63;
  int n0 = wid * 16;
  if (n0 >= nN) return;
  int row = lane & 15;
  int kb  = lane >> 4;
  int nr  = min(n0 + row, nN-1);

  short8v a[4];
#pragma unroll
  for (int ks=0; ks<4; ks++)
    a[ks] = *reinterpret_cast<const short8v*>(
        reinterpret_cast<const short*>(uv + (size_t)nr*128 + ks*32 + kb*8));

  f32x4 acc[4];
#pragma unroll
  for (int nt=0; nt<4; nt++){
    f32x4 c = {0.f,0.f,0.f,0.f};
#pragma unroll
    for (int ks=0; ks<4; ks++){
      short8v b = *reinterpret_cast<const short8v*>(
          reinterpret_cast<const short*>(bfrag) + (((size_t)nt*4 + ks)*64 + lane)*8);
      c = __builtin_amdgcn_mfma_f32_16x16x32_bf16(a[ks], b, c, 0, 0, 0);
    }
    acc[nt] = c;
  }

  if (!FINAL){
#pragma unroll
    for (int r=0;r<4;r++){
      int n = n0 + kb*4 + r;
      if (n < nN){
#pragma unroll
        for (int nt=0;nt<4;nt++)
          out[(size_t)n*64 + nt*16 + row] = acc[nt][r];
      }
    }
  } else {
    // x_out[n] = relu(acc)·Wnc[t[n]] + bnc[t[n]]
#pragma unroll
    for (int r=0;r<4;r++){
      int n = n0 + kb*4 + r;
      bool valid = (n < nN);
      int t = valid ? ntype[n] : 0;
      float pe = 0.f;
#pragma unroll
      for (int nt=0;nt<4;nt++)
        pe = fmaf(fmaxf(acc[nt][r],0.f), Wnc[t*64 + nt*16 + row], pe);
#pragma unroll
      for (int m=1;m<16;m<<=1) pe += __shfl_xor(pe, m);
      if (row == 0 && valid) xout[n] = pe + bnc[t];
    }
  }
}

extern "C" void kernel_launch(void* const* d_in, const int* in_sizes, int n_in,
                              void* d_out, int out_size, void* d_ws, size_t ws_size,
                              hipStream_t stream) {
  const float* x      = (const float*)d_in[0];
  const int*   eidx   = (const int*) d_in[1];
  const int*   ntype  = (const int*) d_in[2];
  const int*   etype  = (const int*) d_in[3];
  const float* eattr  = (const float*)d_in[4];
  const float* Whl[3]  = {(const float*)d_in[5],  (const float*)d_in[11], (const float*)d_in[17]};
  const float* bhl[3]  = {(const float*)d_in[6],  (const float*)d_in[12], (const float*)d_in[18]};
  const float* Ete[3]  = {(const float*)d_in[7],  (const float*)d_in[13], (const float*)d_in[19]};
  const float* Wea[3]  = {(const float*)d_in[8],  (const float*)d_in[14], (const float*)d_in[20]};
  const float* Watt[3] = {(const float*)d_in[9],  (const float*)d_in[15], (const float*)d_in[21]};
  const float* Wlin[3] = {(const float*)d_in[10], (const float*)d_in[16], (const float*)d_in[22]};
  const float* Wnc = (const float*)d_in[23];
  const float* bnc = (const float*)d_in[24];
  const float* Wec = (const float*)d_in[25];
  const float* bec = (const float*)d_in[26];

  const int nN = in_sizes[2];      // 50000
  const int nE = in_sizes[3];      // 800000
  const int* srcI = eidx;
  const int* dstI = eidx + nE;

  // workspace layout (f32 words)
  float* ws = (float*)d_ws;
  size_t o = 0;
  bf16*  h      = (bf16*)(ws + o); o += (size_t)nN*32;   // [N][64] bf16
  float* outA   = ws + o;                                 // [N][64] f32, ALIASES uv below
  bf16*  uv     = (bf16*)(ws + o); o += (size_t)nN*64;   // [N][128] bf16 (same bytes as outA)
  float* hi_s   = ws + o;          o += (size_t)nN;
  float* hj_s   = ws + o;          o += (size_t)nN;
  float* exS    = ws + o;          o += (size_t)nE;      // exp(logit), sorted order
  bf16*  eaS    = (bf16*)(ws + o); o += (size_t)nE*32;   // [E][64] bf16, SORTED, in-place across layers
  int*   deg    = (int*)(ws + o);  o += (size_t)nN;
  int*   off    = (int*)(ws + o);  o += (size_t)nN + 1;
  int*   eid    = (int*)(ws + o);  o += (size_t)nE;
  int*   srcP   = (int*)(ws + o);  o += (size_t)nE;
  int*   dstP   = (int*)(ws + o);  o += (size_t)nE;
  int*   etyP   = (int*)(ws + o);  o += (size_t)nE;
  o = (o + 3) & ~(size_t)3;                              // 16B align
  bf16*  bfrag  = (bf16*)(ws + o); o += (size_t)4096;    // up to 4nt*4ks*64*8 bf16 = 16KB

  dim3 blk(256);
  int nodeWB = (int)(((size_t)nN*64 + 255)/256);   // wave-per-node
  int edgeTB = (nE + 255)/256;                     // thread-per-edge
  int eaMB   = (int)(((size_t)((nE+31)/32)*64 + 255)/256); // wave per 32 edges
  int mmMB   = (int)(((size_t)((nN+15)/16)*64 + 255)/256); // wave per 16 nodes

  // ---- CSR build + permuted index arrays (once; dst is layer-invariant) ----
  hipMemsetAsync(deg, 0, (size_t)nN*4, stream);
  k_hist<<<edgeTB, blk, 0, stream>>>(dstI, deg, nE);
  k_scan<<<1, 1024, 0, stream>>>(deg, off, nN);
  hipMemsetAsync(deg, 0, (size_t)nN*4, stream);
  k_scatter<<<edgeTB, blk, 0, stream>>>(dstI, off, deg, eid, nE);
  k_perm<<<edgeTB, blk, 0, stream>>>(eid, srcI, dstI, etype, srcP, dstP, etyP, nE);

  float* xout = (float*)d_out;

  for (int L = 0; L < 3; ++L) {
    if (L == 0)
      k_hlin<float,false><<<nodeWB, blk, 0, stream>>>(x,    ntype, Whl[L], bhl[L], Watt[L], h, hi_s, hj_s, nN);
    else
      k_hlin<float,true ><<<nodeWB, blk, 0, stream>>>(outA, ntype, Whl[L], bhl[L], Watt[L], h, hi_s, hj_s, nN);

    int KS = (L==0) ? 1 : 2;
    k_bfrag<<<(4*KS*64 + 255)/256, blk, 0, stream>>>(Wea[L], bfrag, KS);
    if (L == 0)
      k_ea_mfma<0><<<eaMB, blk, 0, stream>>>(eattr, eid, bfrag, Watt[L], srcP, dstP, etyP, Ete[L],
                                             hi_s, hj_s, eaS, exS, nullptr, nullptr, nullptr, nE);
    else if (L == 1)
      k_ea_mfma<1><<<eaMB, blk, 0, stream>>>(eaS, eid, bfrag, Watt[L], srcP, dstP, etyP, Ete[L],
                                             hi_s, hj_s, eaS, exS, nullptr, nullptr, nullptr, nE);
    else
      k_ea_mfma<2><<<eaMB, blk, 0, stream>>>(eaS, eid, bfrag, Watt[L], srcP, dstP, etyP, Ete[L],
                                             hi_s, hj_s, eaS, exS, Wec, bec, xout + nN, nE);

    k_agg<<<nodeWB, blk, 0, stream>>>(off, srcP, h, eaS, exS, uv, nN);

    k_bfrag<<<(4*4*64 + 255)/256, blk, 0, stream>>>(Wlin[L], bfrag, 4);
    if (L < 2)
      k_mm_mfma<false><<<mmMB, blk, 0, stream>>>(uv, bfrag, outA, nullptr, nullptr, nullptr, nullptr, nN);
    else
      k_mm_mfma<true ><<<mmMB, blk, 0, stream>>>(uv, bfrag, nullptr, ntype, Wnc, bnc, xout, nN);
  }
}